// Round 10
// baseline (641.874 us; speedup 1.0000x reference)
//
#include <hip/hip_runtime.h>
#include <stdint.h>

// FCOS head, MI355X. Implicit-GEMM conv3x3 via bf16 MFMA (16x16x32).
// Activations plane-blocked [plane=ch>>3][pos][16B] (XP stride) everywhere.
// R6: coalesced B staging (163->107 us; conv was VMEM line-request-bound).
// R8/R9: plane-blocked Y + plane GN; gn_apply grid bug (10907 vs 10912) was
//   the SOLE cause of the R7/R8 failures (identical absmax across different
//   conv kernels). R9 = 600 us, conv 103 us @ MfmaUtil 45%.
// R9 analysis: conv is LDS-read-throughput bound (96 KB/round @ ~85 B/cyc
//   = 1130 cyc vs 931 cyc MFMA). Fix: wider wave tile.
// R10: tower convs = conv_t256 (128x256 block, 4 waves of 64x128, acc[4][8],
//   0.375 KB LDS read/MFMA, 3x24KB ring = 72KB dynamic, vmcnt(6) counted).
//   Retry of R7's kernel, now exonerated. mode-1 conv + GN kernels R9-exact.
// R2/R3: no stats fusion in conv epilogue. R5: no cooperative GN.

typedef __attribute__((ext_vector_type(8))) short short8;
typedef __attribute__((ext_vector_type(4))) float floatx4;

#define XP 349184            // plane stride bytes = 21824 * 16
#define TIB (32 * XP)        // per (tower,img) block = 11,173,888 B

__device__ __forceinline__ unsigned short f2bf(float f) {
  unsigned u = __float_as_uint(f);
  u = (u + 0x7FFFu + ((u >> 16) & 1u)) >> 16;   // RNE
  return (unsigned short)u;
}
__device__ __forceinline__ unsigned pk2(float a, float b) {
  return (unsigned)f2bf(a) | ((unsigned)f2bf(b) << 16);
}
__device__ __forceinline__ void async16(const void* g, void* l) {
  __builtin_amdgcn_global_load_lds(
      (const __attribute__((address_space(1))) unsigned int*)g,
      (__attribute__((address_space(3))) unsigned int*)l, 16, 0, 0);
}

// s_waitcnt imm16 (gfx9 enc): vmcnt[3:0]|[15:14], expcnt[6:4], lgkmcnt[11:8]
#define WAIT_VM4 0x0F74   // vmcnt(4)
#define WAIT_VM6 0x0F76   // vmcnt(6)
#define WAIT_VM0 0x0F70   // vmcnt(0)

// level geometry (fixed by problem): W = 1<<lw, HW = 1<<(2lw)
__device__ const int d_lw[5]   = {7, 6, 5, 4, 3};
__device__ const int d_off[5]  = {0, 16384, 20480, 21504, 21760};
__device__ const int d_nt[5]   = {128, 32, 8, 2, 1};           // ceil(HW/128)
__device__ const int d_cumT[6] = {0, 1024, 1280, 1344, 1360, 1368}; // legacy mode0
__device__ const int d_cumO[6] = {0, 512, 640, 672, 680, 684};      // 4*nt per level
__device__ const int d_cumS[6] = {0, 256, 320, 336, 340, 341};      // HW/64 tiles
// conv_t256 geometry: 256-pos tiles, 8 = mt x img x tower combos per tile
__device__ const int d_nt2[5]  = {64, 16, 4, 1, 1};
__device__ const int d_cum2[6] = {0, 512, 640, 672, 680, 688};
// gn_stats chunk table: 13 chunks x (lvl, pos0, len)
__device__ const int ck_lvl[13] = {0,0,0,0,0,0,0,0,1,1,2,3,4};
__device__ const int ck_c0[13]  = {0,2048,4096,6144,8192,10240,12288,14336,0,2048,0,0,0};
__device__ const int ck_len[13] = {2048,2048,2048,2048,2048,2048,2048,2048,2048,2048,1024,256,64};

// ---------------------------------------------------------------------------
// init: zero page (OOB source for global_load_lds) + 3 stage stats arrays.
__global__ void zpk(float* zp, float* stats) {
  for (int i = threadIdx.x; i < 384; i += 256) zp[i] = 0.f;
  for (int i = threadIdx.x; i < 1920; i += 256) stats[i] = 0.f;
}

// ---------------------------------------------------------------------------
// weight transform: fp32 [O][I][3][3] -> bf16 blocked [mt][cc][tap][cs][m][8]
__global__ __launch_bounds__(256) void wtrans(
    const float* __restrict__ c0, const float* __restrict__ c1, const float* __restrict__ c2,
    const float* __restrict__ r0, const float* __restrict__ r1, const float* __restrict__ r2,
    const float* __restrict__ cw, const float* __restrict__ rw, const float* __restrict__ tw,
    unsigned short* __restrict__ dst) {
  const int z = blockIdx.y;
  const int nel = (z < 6) ? 589824 : 294912;
  const int idx = blockIdx.x * 256 + threadIdx.x;
  if (idx >= nel) return;
  int tmp = idx;
  const int j = tmp & 7;   tmp >>= 3;
  const int m = tmp & 127; tmp >>= 7;
  const int cs = tmp & 3;  tmp >>= 2;
  const int t = tmp % 9;   tmp /= 9;     // tap inner
  const int cc = tmp & 7;  const int mt = tmp >> 3;
  const int o = mt * 128 + m;
  const int i = cc * 32 + cs * 8 + j;
  float v = 0.f;
  const float* srcs[6] = {c0, c1, c2, r0, r1, r2};
  if (z < 6)      v = srcs[z][((size_t)o * 256 + i) * 9 + t];
  else if (z == 6){ if (o < 80) v = cw[((size_t)o * 256 + i) * 9 + t]; }
  else            { if (o < 4)  v = rw[((size_t)o * 256 + i) * 9 + t];
                    else if (o == 4) v = tw[(size_t)i * 9 + t]; }
  const size_t base = (z < 6) ? (size_t)z * 589824
                              : (size_t)6 * 589824 + (size_t)(z - 6) * 294912;
  dst[base + idx] = f2bf(v);
}

// ---------------------------------------------------------------------------
// feature NCHW fp32 -> plane-blocked bf16 (R6-exact).
__global__ __launch_bounds__(256) void feat_nhwc(
    const float* __restrict__ s0, const float* __restrict__ s1,
    const float* __restrict__ s2, const float* __restrict__ s3,
    const float* __restrict__ s4, unsigned short* __restrict__ dst) {
  __shared__ unsigned short tile[64][65];
  int bx = blockIdx.x, lvl = 0;
  while (bx >= d_cumS[lvl + 1]) ++lvl;
  const int HW = 1 << (2 * d_lw[lvl]), off = d_off[lvl];
  const float* srcs[5] = {s0, s1, s2, s3, s4};
  const float* src = srcs[lvl];
  const int img = blockIdx.z, c0 = blockIdx.y * 64, p0 = (bx - d_cumS[lvl]) * 64;
  const float* s = src + ((size_t)img * 256 + c0) * HW + p0;
  const int tid = threadIdx.x;
#pragma unroll
  for (int i = 0; i < 4; i++) {
    const int cl = (tid >> 4) + i * 16, pl = (tid & 15) * 4;
    const float4 v = *(const float4*)(s + (size_t)cl * HW + pl);
    tile[cl][pl]     = f2bf(v.x);
    tile[cl][pl + 1] = f2bf(v.y);
    tile[cl][pl + 2] = f2bf(v.z);
    tile[cl][pl + 3] = f2bf(v.w);
  }
  __syncthreads();
  const int pl = tid >> 2, cseg = (tid & 3) * 16;
  unsigned ro[8];
#pragma unroll
  for (int k = 0; k < 8; k++)
    ro[k] = (unsigned)tile[cseg + 2 * k][pl] | ((unsigned)tile[cseg + 2 * k + 1][pl] << 16);
  const int ch0 = c0 + cseg;                      // multiple of 16
  char* db = (char*)dst + (size_t)img * TIB + (size_t)(ch0 >> 3) * XP
           + (size_t)(off + p0 + pl) * 16;
  uint4 u0 = {ro[0], ro[1], ro[2], ro[3]};
  uint4 u1 = {ro[4], ro[5], ro[6], ro[7]};
  *(uint4*)db = u0;
  *(uint4*)(db + XP) = u1;
}

// ---------------------------------------------------------------------------
// conv3x3 implicit GEMM (R9-exact). mode 0: tower conv -> plane-blocked Y
// (unused in R10 launches but kept). mode 1: output convs -> d_out.
__global__ __launch_bounds__(256) void conv_mfma(
    const unsigned short* __restrict__ xin0, const unsigned short* __restrict__ xin1,
    const unsigned short* __restrict__ wA, const unsigned short* __restrict__ wB,
    unsigned short* __restrict__ y0, unsigned short* __restrict__ y1,
    const float* __restrict__ cb0, const float* __restrict__ cb1,
    float* __restrict__ out,
    const float* __restrict__ ob_cls, const float* __restrict__ ob_reg, const float* __restrict__ ob_ctr,
    const unsigned short* __restrict__ zp, int mode) {
  __shared__ __align__(16) char smem[49152];   // 3 buffers x (A 8K | B 8K)
  const int tid = threadIdx.x;
  const int* cum = (mode == 0) ? d_cumT : d_cumO;
  const int nwg = (mode == 0) ? 1368 : 684;
  const int xcd = blockIdx.x & 7, cidx = blockIdx.x >> 3;
  const int qq = nwg >> 3, rr = nwg & 7;
  int bid = (xcd < rr ? xcd * (qq + 1) : rr * (qq + 1) + (xcd - rr) * qq) + cidx;
  int lvl = 0;
  while (bid >= cum[lvl + 1]) ++lvl;
  int r = bid - cum[lvl];
  const int lw = d_lw[lvl], W = 1 << lw, HW = 1 << (2 * lw), poffl = d_off[lvl];
  const int ntc = d_nt[lvl];
  const int nt = r % ntc; r /= ntc;
  int mt = 0;
  if (mode == 0) { mt = r & 1; r >>= 1; }
  const int img = r & 1, tower = r >> 1;

  const unsigned short* xin = (tower ? xin1 : xin0) + (size_t)img * 21824 * 256;
  const unsigned short* wset = tower ? wB : wA;

  const int n = tid & 127;
  const int p = nt * 128 + n;
  const bool pv = p < HW;
  const int h = p >> lw, w = p & (W - 1);
  const int kq = tid >> 7;

  const char* xb = (const char*)xin;
  const char* tb[9];
  int stp[9];
#pragma unroll
  for (int t = 0; t < 9; t++) {
    const int rr2 = h + t / 3 - 1, cx = w + t % 3 - 1;
    const bool v = pv && rr2 >= 0 && rr2 < W && cx >= 0 && cx < W;
    tb[t] = v ? xb + (size_t)kq * XP + (size_t)(poffl + rr2 * W + cx) * 16
              : (const char*)zp;
    stp[t] = v ? 4 * XP : 0;
  }

  const char* abase = (const char*)wset + (size_t)mt * 589824;
  const char* a_tid = abase + (size_t)tid * 16;
  char* l_tid = smem + tid * 16;

  const int lane = tid & 63, q = lane >> 4, lr = lane & 15;
  const int wv = tid >> 6, wm = wv >> 1, wn = wv & 1;
  int aoff[4], boff[4];
#pragma unroll
  for (int i = 0; i < 4; i++) {
    aoff[i] = ((q << 7) + wm * 64 + i * 16 + lr) << 4;
    boff[i] = (((q << 7) + wn * 64 + i * 16 + lr) << 4) + 8192;
  }

  floatx4 acc[4][4];
#pragma unroll
  for (int i = 0; i < 4; i++)
#pragma unroll
    for (int j = 0; j < 4; j++) acc[i][j] = (floatx4){0.f, 0.f, 0.f, 0.f};

#define UNIT(CC, U, WIMM)                                                     \
  {                                                                           \
    const int it_ = (CC) * 9 + (U);                                           \
    __builtin_amdgcn_s_waitcnt(WIMM);                                         \
    __builtin_amdgcn_s_barrier();                                             \
    asm volatile("" ::: "memory");                                            \
    if (it_ + 2 < 72) {                                                       \
      const int nu_ = (U) + 2;                                                \
      const int tn_ = nu_ % 9;            /* compile-time */                  \
      const int ccn_ = (CC) + nu_ / 9;                                        \
      char* la_ = l_tid + (nu_ % 3) * 16384;                                  \
      const char* ap_ = a_tid + (size_t)(it_ + 2) * 8192;                     \
      async16(ap_, la_);                                                      \
      async16(ap_ + 4096, la_ + 4096);                                        \
      const int sp_ = stp[tn_];                                               \
      const char* bp_ = tb[tn_] + ccn_ * sp_;                                 \
      async16(bp_, la_ + 8192);                                               \
      async16(bp_ + (sp_ >> 1), la_ + 12288);                                 \
    }                                                                         \
    asm volatile("" ::: "memory");                                            \
    const int sb_ = ((U) % 3) * 16384;                                        \
    short8 af[4], bfr[4];                                                     \
    _Pragma("unroll")                                                         \
    for (int i = 0; i < 4; i++) {                                             \
      af[i] = *(const short8*)(smem + sb_ + aoff[i]);                         \
      bfr[i] = *(const short8*)(smem + sb_ + boff[i]);                        \
    }                                                                         \
    _Pragma("unroll")                                                         \
    for (int i = 0; i < 4; i++)                                               \
      _Pragma("unroll")                                                       \
      for (int j = 0; j < 4; j++)                                             \
        acc[i][j] = __builtin_amdgcn_mfma_f32_16x16x32_bf16(af[i], bfr[j],    \
                                                            acc[i][j], 0, 0, 0); \
  }

  async16(a_tid, l_tid);
  async16(a_tid + 4096, l_tid + 4096);
  async16(tb[0], l_tid + 8192);
  async16(tb[0] + (stp[0] >> 1), l_tid + 12288);
  async16(a_tid + 8192, l_tid + 16384);
  async16(a_tid + 12288, l_tid + 20480);
  async16(tb[1], l_tid + 24576);
  async16(tb[1] + (stp[1] >> 1), l_tid + 28672);

  for (int cc = 0; cc < 7; ++cc) {
#pragma unroll
    for (int u = 0; u < 9; ++u) UNIT(cc, u, WAIT_VM4)
  }
  UNIT(7, 0, WAIT_VM4) UNIT(7, 1, WAIT_VM4) UNIT(7, 2, WAIT_VM4)
  UNIT(7, 3, WAIT_VM4) UNIT(7, 4, WAIT_VM4) UNIT(7, 5, WAIT_VM4)
  UNIT(7, 6, WAIT_VM4) UNIT(7, 7, WAIT_VM0) UNIT(7, 8, WAIT_VM0)
#undef UNIT

  if (mode == 0) {
    char* yb = (char*)(tower ? y1 : y0) + (size_t)img * TIB;
    const float* cb = tower ? cb1 : cb0;
#pragma unroll
    for (int i = 0; i < 4; i++) {
      const int c = mt * 128 + wm * 64 + i * 16 + (q << 2);
      const float4 b4 = *(const float4*)(cb + c);
      char* yp = yb + (size_t)(c >> 3) * XP + (size_t)poffl * 16 + ((c & 7) << 1);
#pragma unroll
      for (int j = 0; j < 4; j++) {
        const int pp = nt * 128 + wn * 64 + j * 16 + lr;
        if (pp >= HW) continue;
        floatx4 a = acc[i][j];
        uint2 u;
        u.x = pk2(a.x + b4.x, a.y + b4.y);
        u.y = pk2(a.z + b4.z, a.w + b4.w);
        *(uint2*)(yp + (size_t)pp * 16) = u;
      }
    }
  } else {
#pragma unroll
    for (int j = 0; j < 4; j++) {
      const int pp = nt * 128 + wn * 64 + j * 16 + lr;
      if (pp >= HW) continue;
      const size_t gp = (size_t)poffl + pp;
#pragma unroll
      for (int i = 0; i < 4; i++) {
        const int m0 = wm * 64 + i * 16 + (q << 2);
        floatx4 a = acc[i][j];
#pragma unroll
        for (int k2 = 0; k2 < 4; k2++) {
          const int m = m0 + k2;
          const float v = a[k2];
          if (tower == 0) {
            if (m < 80) out[((size_t)img * 85 + m) * 21824 + gp] = v + ob_cls[m];
          } else {
            if (m < 4)
              out[((size_t)img * 85 + 80 + m) * 21824 + gp] = fmaxf(v + ob_reg[m], 0.f);
            else if (m == 4)
              out[((size_t)img * 85 + 84) * 21824 + gp] = v + ob_ctr[0];
          }
        }
      }
    }
  }
}

// ---------------------------------------------------------------------------
// Tower conv, 128x256 tile: 4 waves of 64x128 (acc[4][8]). 3-buffer ring of
// (A 8K | B 16K) = 72KB dynamic LDS, 2 blocks/CU. 6 loads/unit -> vmcnt(6).
// B staged per-plane fully coalesced. Plane-blocked Y out (+bias, bf16).
__global__ __launch_bounds__(256, 2) void conv_t256(
    const unsigned short* __restrict__ xin0, const unsigned short* __restrict__ xin1,
    const unsigned short* __restrict__ wA, const unsigned short* __restrict__ wB,
    unsigned short* __restrict__ y0, unsigned short* __restrict__ y1,
    const float* __restrict__ cb0, const float* __restrict__ cb1,
    const unsigned short* __restrict__ zp) {
  extern __shared__ __align__(16) char smem[];   // 3 x (A 8192 | B 16384)
  const int tid = threadIdx.x;
  // XCD-chunked swizzle: 688 = 8*86 exact
  const int xcd = blockIdx.x & 7, cidx = blockIdx.x >> 3;
  int bid = xcd * 86 + cidx;
  int lvl = 0;
  while (bid >= d_cum2[lvl + 1]) ++lvl;
  int r = bid - d_cum2[lvl];
  const int lw = d_lw[lvl], W = 1 << lw, HW = 1 << (2 * lw), poffl = d_off[lvl];
  const int ntc = d_nt2[lvl];
  const int nt = r % ntc; r /= ntc;
  const int mt = r & 1; r >>= 1;
  const int img = r & 1, tower = r >> 1;

  const char* xb = (const char*)((tower ? xin1 : xin0)) + (size_t)img * TIB;
  const unsigned short* wset = tower ? wB : wA;

  // staged B position: one pos per thread
  const int p = nt * 256 + tid;
  const bool pv = p < HW;
  const int h = p >> lw, w = p & (W - 1);

  const char* tb[9];
  int stp[9];
#pragma unroll
  for (int t = 0; t < 9; t++) {
    const int rr2 = h + t / 3 - 1, cx = w + t % 3 - 1;
    const bool v = pv && rr2 >= 0 && rr2 < W && cx >= 0 && cx < W;
    tb[t] = v ? xb + (size_t)(poffl + rr2 * W + cx) * 16 : (const char*)zp;
    stp[t] = v ? XP : 0;
  }

  const char* abase = (const char*)wset + (size_t)mt * 589824;
  const char* a_tid = abase + (size_t)tid * 16;
  char* l_tid = smem + tid * 16;

  const int lane = tid & 63, q = lane >> 4, lr = lane & 15;
  const int wv = tid >> 6, wm = wv >> 1, wn = wv & 1;  // wave tile 64(M) x 128(N)
  int aoff[4], boff[8];
#pragma unroll
  for (int i = 0; i < 4; i++)
    aoff[i] = ((q << 7) + wm * 64 + i * 16 + lr) << 4;
#pragma unroll
  for (int j = 0; j < 8; j++)
    boff[j] = 8192 + (((q << 8) + wn * 128 + j * 16 + lr) << 4);

  floatx4 acc[4][8];
#pragma unroll
  for (int i = 0; i < 4; i++)
#pragma unroll
    for (int j = 0; j < 8; j++) acc[i][j] = (floatx4){0.f, 0.f, 0.f, 0.f};

  // Unit it = cc*9 + t: A 8KB at a_tid + it*8192; B = 4 planes (cc*4+m) of
  // tap t, 256 pos x 16B each. Buffer = it%3 (stride 24576). 6 loads/unit.
#define TUNIT(CC, U, WIMM)                                                    \
  {                                                                           \
    const int it_ = (CC) * 9 + (U);                                           \
    __builtin_amdgcn_s_waitcnt(WIMM);                                         \
    __builtin_amdgcn_s_barrier();                                             \
    asm volatile("" ::: "memory");                                            \
    if (it_ + 2 < 72) {                                                       \
      const int nu_ = (U) + 2;                                                \
      const int tn_ = nu_ % 9;            /* compile-time */                  \
      const int ccn_ = (CC) + nu_ / 9;                                        \
      char* la_ = l_tid + (nu_ % 3) * 24576;                                  \
      const char* ap_ = a_tid + (size_t)(it_ + 2) * 8192;                     \
      async16(ap_, la_);                                                      \
      async16(ap_ + 4096, la_ + 4096);                                        \
      const int sp_ = stp[tn_];                                               \
      const char* bp_ = tb[tn_] + ccn_ * 4 * sp_;                             \
      async16(bp_, la_ + 8192);                                               \
      async16(bp_ + sp_, la_ + 12288);                                        \
      async16(bp_ + 2 * sp_, la_ + 16384);                                    \
      async16(bp_ + 3 * sp_, la_ + 20480);                                    \
    }                                                                         \
    asm volatile("" ::: "memory");                                            \
    const int sb_ = ((U) % 3) * 24576;                                        \
    short8 af[4], bfr[8];                                                     \
    _Pragma("unroll")                                                         \
    for (int i = 0; i < 4; i++) af[i] = *(const short8*)(smem + sb_ + aoff[i]); \
    _Pragma("unroll")                                                         \
    for (int j = 0; j < 8; j++) bfr[j] = *(const short8*)(smem + sb_ + boff[j]); \
    _Pragma("unroll")                                                         \
    for (int i = 0; i < 4; i++)                                               \
      _Pragma("unroll")                                                       \
      for (int j = 0; j < 8; j++)                                             \
        acc[i][j] = __builtin_amdgcn_mfma_f32_16x16x32_bf16(af[i], bfr[j],    \
                                                            acc[i][j], 0, 0, 0); \
  }

  // prologue: stage units 0 and 1 into buffers 0 and 1
  async16(a_tid, l_tid);
  async16(a_tid + 4096, l_tid + 4096);
  async16(tb[0], l_tid + 8192);
  async16(tb[0] + stp[0], l_tid + 12288);
  async16(tb[0] + 2 * stp[0], l_tid + 16384);
  async16(tb[0] + 3 * stp[0], l_tid + 20480);
  async16(a_tid + 8192, l_tid + 24576);
  async16(a_tid + 12288, l_tid + 28672);
  async16(tb[1], l_tid + 32768);
  async16(tb[1] + stp[1], l_tid + 36864);
  async16(tb[1] + 2 * stp[1], l_tid + 40960);
  async16(tb[1] + 3 * stp[1], l_tid + 45056);

  for (int cc = 0; cc < 7; ++cc) {
#pragma unroll
    for (int u = 0; u < 9; ++u) TUNIT(cc, u, WAIT_VM6)
  }
  TUNIT(7, 0, WAIT_VM6) TUNIT(7, 1, WAIT_VM6) TUNIT(7, 2, WAIT_VM6)
  TUNIT(7, 3, WAIT_VM6) TUNIT(7, 4, WAIT_VM6) TUNIT(7, 5, WAIT_VM6)
  TUNIT(7, 6, WAIT_VM6) TUNIT(7, 7, WAIT_VM0) TUNIT(7, 8, WAIT_VM0)
#undef TUNIT

  // epilogue: +bias -> bf16, plane-blocked Y (R9-verified form)
  char* yb = (char*)(tower ? y1 : y0) + (size_t)img * TIB;
  const float* cb = tower ? cb1 : cb0;
#pragma unroll
  for (int i = 0; i < 4; i++) {
    const int c = mt * 128 + wm * 64 + i * 16 + (q << 2);
    const float4 b4 = *(const float4*)(cb + c);
    char* yp = yb + (size_t)(c >> 3) * XP + (size_t)poffl * 16 + ((c & 7) << 1);
#pragma unroll
    for (int j = 0; j < 8; j++) {
      const int pp = nt * 256 + wn * 128 + j * 16 + lr;
      if (pp >= HW) continue;
      floatx4 a = acc[i][j];
      uint2 u;
      u.x = pk2(a.x + b4.x, a.y + b4.y);
      u.y = pk2(a.z + b4.z, a.w + b4.w);
      *(uint2*)(yp + (size_t)pp * 16) = u;
    }
  }
}

// ---------------------------------------------------------------------------
// GN stats over plane-blocked Y (R9-exact). Block = (chunk, group, tz).
__global__ __launch_bounds__(256) void gn_stats(
    const unsigned short* __restrict__ y0, const unsigned short* __restrict__ y1,
    float* __restrict__ stats) {
  const int ck = blockIdx.x, g = blockIdx.y, tz = blockIdx.z;
  const int tower = tz >> 1, img = tz & 1;
  const int lvl = ck_lvl[ck], c0 = ck_c0[ck], len = ck_len[ck];
  const char* base = (const char*)(tower ? y1 : y0) + (size_t)img * TIB
                   + (size_t)(2 * g) * XP + (size_t)(d_off[lvl] + c0) * 16;
  const int tid = threadIdx.x;
  float s = 0.f, s2 = 0.f;
  const int n2 = 2 * len;
  for (int i = tid; i < n2; i += 256) {
    const int pl = (i >= len);
    const int pos = i - pl * len;
    const uint4 d = *(const uint4*)(base + (size_t)pl * XP + (size_t)pos * 16);
    unsigned uu[4] = {d.x, d.y, d.z, d.w};
#pragma unroll
    for (int k = 0; k < 4; k++) {
      const float f0 = __uint_as_float(uu[k] << 16);
      const float f1 = __uint_as_float(uu[k] & 0xFFFF0000u);
      s += f0 + f1;
      s2 += f0 * f0 + f1 * f1;
    }
  }
#pragma unroll
  for (int m = 1; m < 64; m <<= 1) {
    s += __shfl_xor(s, m);
    s2 += __shfl_xor(s2, m);
  }
  __shared__ float rs[4], rq[4];
  const int lane = tid & 63, wvv = tid >> 6;
  if (lane == 0) { rs[wvv] = s; rq[wvv] = s2; }
  __syncthreads();
  if (tid == 0) {
    float* st = stats + (((tz * 5 + lvl) * 16 + g) << 1);
    atomicAdd(st, rs[0] + rs[1] + rs[2] + rs[3]);
    atomicAdd(st + 1, rq[0] + rq[1] + rq[2] + rq[3]);
  }
}

// ---------------------------------------------------------------------------
// GN apply + affine + ReLU + bf16: Y (plane) -> X (plane). Thread = one 16B
// slot. grid MUST be 10912 = 4 ti x 32 planes x 21824 pos / 256.
__global__ __launch_bounds__(256) void gn_apply(
    const unsigned short* __restrict__ ybase, unsigned short* __restrict__ xbase,
    const float* __restrict__ stats,
    const float* __restrict__ g0, const float* __restrict__ b0,
    const float* __restrict__ g1, const float* __restrict__ b1) {
  const int g = blockIdx.x * 256 + threadIdx.x;   // 0..2,793,471 exact
  const int pos = g % 21824;
  const int rest = g / 21824;                     // 0..127
  const int plane = rest & 31;
  const int ti = rest >> 5;                       // tower*2+img
  const int tower = ti >> 1;
  const int lvl = (pos >= 16384) + (pos >= 20480) + (pos >= 21504) + (pos >= 21760);
  const float cnt = (float)(16 << (2 * d_lw[lvl]));
  const float* st = stats + ((((ti * 5 + lvl) * 16 + (plane >> 1))) << 1);
  const float mean = st[0] / cnt;
  const float var = st[1] / cnt - mean * mean;
  const float rstd = rsqrtf(var + 1e-5f);
  const float* gam = (tower ? g1 : g0) + plane * 8;
  const float* bet = (tower ? b1 : b0) + plane * 8;
  const size_t off = (size_t)ti * TIB + (size_t)plane * XP + (size_t)pos * 16;
  const uint4 d = *(const uint4*)((const char*)ybase + off);
  unsigned uu[4] = {d.x, d.y, d.z, d.w};
  unsigned ro[4];
#pragma unroll
  for (int k = 0; k < 4; k++) {
    const float f0 = __uint_as_float(uu[k] << 16);
    const float f1 = __uint_as_float(uu[k] & 0xFFFF0000u);
    const float o0 = fmaxf((f0 - mean) * rstd * gam[2 * k] + bet[2 * k], 0.f);
    const float o1 = fmaxf((f1 - mean) * rstd * gam[2 * k + 1] + bet[2 * k + 1], 0.f);
    ro[k] = (unsigned)f2bf(o0) | ((unsigned)f2bf(o1) << 16);
  }
  uint4 od = {ro[0], ro[1], ro[2], ro[3]};
  *(uint4*)((char*)xbase + off) = od;
}

// ---------------------------------------------------------------------------
extern "C" void kernel_launch(void* const* d_in, const int* in_sizes, int n_in,
                              void* d_out, int out_size, void* d_ws, size_t ws_size,
                              hipStream_t stream) {
  (void)in_sizes; (void)n_in; (void)out_size; (void)ws_size;
  char* ws = (char*)d_ws;
  unsigned short* zp = (unsigned short*)ws;                 // 1536 B zeros
  unsigned short* wblk = (unsigned short*)(ws + 2048);      // 8,257,536 B
  const size_t WSET_T = 1179648;                            // bytes per tower set
  const size_t WSET_O = 589824;                             // bytes per out set
  char* pXfeat = ws + 2048 + 6 * WSET_T + 2 * WSET_O;
  const size_t XSZ = (size_t)2 * 21824 * 256 * 2;           // 22,347,776 B
  char* pX = pXfeat + XSZ;                                  // 2 towers
  char* pY = pX + 2 * XSZ;                                  // 2 towers
  float* stats = (float*)(pY + 2 * XSZ);                    // 3 stages x 640 floats

  // 72 KB dynamic LDS for conv_t256
  hipFuncSetAttribute(reinterpret_cast<const void*>(conv_t256),
                      hipFuncAttributeMaxDynamicSharedMemorySize, 73728);

  zpk<<<1, 256, 0, stream>>>((float*)zp, stats);
  wtrans<<<dim3(2304, 8), 256, 0, stream>>>(
      (const float*)d_in[5], (const float*)d_in[9], (const float*)d_in[13],
      (const float*)d_in[17], (const float*)d_in[21], (const float*)d_in[25],
      (const float*)d_in[29], (const float*)d_in[31], (const float*)d_in[33], wblk);
  feat_nhwc<<<dim3(341, 4, 2), 256, 0, stream>>>(
      (const float*)d_in[0], (const float*)d_in[1], (const float*)d_in[2],
      (const float*)d_in[3], (const float*)d_in[4], (unsigned short*)pXfeat);

  unsigned short* xc = (unsigned short*)pX;
  unsigned short* xr = (unsigned short*)(pX + XSZ);
  unsigned short* yc = (unsigned short*)pY;
  unsigned short* yr = (unsigned short*)(pY + XSZ);

  for (int s = 0; s < 3; s++) {
    const unsigned short* in0 = s ? xc : (unsigned short*)pXfeat;
    const unsigned short* in1 = s ? xr : (unsigned short*)pXfeat;
    const unsigned short* wc = wblk + (size_t)s * 589824;        // elem stride per set
    const unsigned short* wr = wblk + (size_t)(3 + s) * 589824;
    float* st_s = stats + (size_t)s * 640;
    conv_t256<<<688, 256, 73728, stream>>>(
        in0, in1, wc, wr, yc, yr,
        (const float*)d_in[6 + 4 * s], (const float*)d_in[18 + 4 * s], zp);
    gn_stats<<<dim3(13, 16, 4), 256, 0, stream>>>(yc, yr, st_s);
    gn_apply<<<10912, 256, 0, stream>>>(
        (const unsigned short*)pY, (unsigned short*)pX, st_s,
        (const float*)d_in[7 + 4 * s], (const float*)d_in[8 + 4 * s],
        (const float*)d_in[19 + 4 * s], (const float*)d_in[20 + 4 * s]);
  }
  const unsigned short* wo_c = wblk + (size_t)6 * 589824;
  const unsigned short* wo_r = wo_c + 294912;
  conv_mfma<<<684, 256, 0, stream>>>(
      xc, xr, wo_c, wo_r, nullptr, nullptr, nullptr, nullptr,
      (float*)d_out, (const float*)d_in[30], (const float*)d_in[32],
      (const float*)d_in[34], zp, 1);
}

// Round 11
// 581.535 us; speedup vs baseline: 1.1038x; 1.1038x over previous
//
#include <hip/hip_runtime.h>
#include <stdint.h>

// FCOS head, MI355X. Implicit-GEMM conv3x3 via bf16 MFMA (16x16x32).
// Activations plane-blocked [plane=ch>>3][pos][16B] (XP stride) everywhere.
// R6: coalesced B staging (163->107 us; conv was VMEM line-request-bound).
// R9: plane-blocked Y + plane GN = 600.6 us, conv 103 us @ MfmaUtil 45%.
// R10 lesson (and R1): at this 72-barrier ring structure, residency
//   (3 blocks/CU, 12 waves) beats wave-tile width -- 128x256@72KB lost 21%
//   (MfmaUtil 45->36). 128x128/48KB is this schedule family's optimum.
// R11: revert to R9 state; drop dead conv_t256 (rule-19 co-compile risk);
//   fold zpk into wtrans (z==8, one fewer dispatch).
// R2/R3: no stats fusion in conv epilogue. R5: no cooperative GN.
// R7/R8: the failures were a gn_apply grid bug (10907 vs 10912), not conv.

typedef __attribute__((ext_vector_type(8))) short short8;
typedef __attribute__((ext_vector_type(4))) float floatx4;

#define XP 349184            // plane stride bytes = 21824 * 16
#define TIB (32 * XP)        // per (tower,img) block = 11,173,888 B

__device__ __forceinline__ unsigned short f2bf(float f) {
  unsigned u = __float_as_uint(f);
  u = (u + 0x7FFFu + ((u >> 16) & 1u)) >> 16;   // RNE
  return (unsigned short)u;
}
__device__ __forceinline__ unsigned pk2(float a, float b) {
  return (unsigned)f2bf(a) | ((unsigned)f2bf(b) << 16);
}
__device__ __forceinline__ void async16(const void* g, void* l) {
  __builtin_amdgcn_global_load_lds(
      (const __attribute__((address_space(1))) unsigned int*)g,
      (__attribute__((address_space(3))) unsigned int*)l, 16, 0, 0);
}

// s_waitcnt imm16 (gfx9 enc): vmcnt[3:0]|[15:14], expcnt[6:4], lgkmcnt[11:8]
#define WAIT_VM4 0x0F74   // vmcnt(4)
#define WAIT_VM0 0x0F70   // vmcnt(0)

// level geometry (fixed by problem): W = 1<<lw, HW = 1<<(2lw)
__device__ const int d_lw[5]   = {7, 6, 5, 4, 3};
__device__ const int d_off[5]  = {0, 16384, 20480, 21504, 21760};
__device__ const int d_nt[5]   = {128, 32, 8, 2, 1};           // ceil(HW/128)
__device__ const int d_cumT[6] = {0, 1024, 1280, 1344, 1360, 1368}; // 8*nt per level
__device__ const int d_cumO[6] = {0, 512, 640, 672, 680, 684};      // 4*nt per level
__device__ const int d_cumS[6] = {0, 256, 320, 336, 340, 341};      // HW/64 tiles
// gn_stats chunk table: 13 chunks x (lvl, pos0, len)
__device__ const int ck_lvl[13] = {0,0,0,0,0,0,0,0,1,1,2,3,4};
__device__ const int ck_c0[13]  = {0,2048,4096,6144,8192,10240,12288,14336,0,2048,0,0,0};
__device__ const int ck_len[13] = {2048,2048,2048,2048,2048,2048,2048,2048,2048,2048,1024,256,64};

// ---------------------------------------------------------------------------
// weight transform: fp32 [O][I][3][3] -> bf16 blocked [mt][cc][tap][cs][m][8]
// z: 0..2 cls_w0..2, 3..5 reg_w0..2, 6 cls_out(pad 80->128), 7 reg_out+ctr
// z==8 (block 0 only): init zero page + stats arrays (was the zpk kernel).
__global__ __launch_bounds__(256) void wtrans(
    const float* __restrict__ c0, const float* __restrict__ c1, const float* __restrict__ c2,
    const float* __restrict__ r0, const float* __restrict__ r1, const float* __restrict__ r2,
    const float* __restrict__ cw, const float* __restrict__ rw, const float* __restrict__ tw,
    unsigned short* __restrict__ dst, float* __restrict__ zp, float* __restrict__ stats) {
  const int z = blockIdx.y;
  if (z == 8) {
    if (blockIdx.x == 0) {
      for (int i = threadIdx.x; i < 384; i += 256) zp[i] = 0.f;
      for (int i = threadIdx.x; i < 1920; i += 256) stats[i] = 0.f;
    }
    return;
  }
  const int nel = (z < 6) ? 589824 : 294912;
  const int idx = blockIdx.x * 256 + threadIdx.x;
  if (idx >= nel) return;
  int tmp = idx;
  const int j = tmp & 7;   tmp >>= 3;
  const int m = tmp & 127; tmp >>= 7;
  const int cs = tmp & 3;  tmp >>= 2;
  const int t = tmp % 9;   tmp /= 9;     // tap inner
  const int cc = tmp & 7;  const int mt = tmp >> 3;
  const int o = mt * 128 + m;
  const int i = cc * 32 + cs * 8 + j;
  float v = 0.f;
  const float* srcs[6] = {c0, c1, c2, r0, r1, r2};
  if (z < 6)      v = srcs[z][((size_t)o * 256 + i) * 9 + t];
  else if (z == 6){ if (o < 80) v = cw[((size_t)o * 256 + i) * 9 + t]; }
  else            { if (o < 4)  v = rw[((size_t)o * 256 + i) * 9 + t];
                    else if (o == 4) v = tw[(size_t)i * 9 + t]; }
  const size_t base = (z < 6) ? (size_t)z * 589824
                              : (size_t)6 * 589824 + (size_t)(z - 6) * 294912;
  dst[base + idx] = f2bf(v);
}

// ---------------------------------------------------------------------------
// feature NCHW fp32 -> plane-blocked bf16 (R6-exact).
__global__ __launch_bounds__(256) void feat_nhwc(
    const float* __restrict__ s0, const float* __restrict__ s1,
    const float* __restrict__ s2, const float* __restrict__ s3,
    const float* __restrict__ s4, unsigned short* __restrict__ dst) {
  __shared__ unsigned short tile[64][65];
  int bx = blockIdx.x, lvl = 0;
  while (bx >= d_cumS[lvl + 1]) ++lvl;
  const int HW = 1 << (2 * d_lw[lvl]), off = d_off[lvl];
  const float* srcs[5] = {s0, s1, s2, s3, s4};
  const float* src = srcs[lvl];
  const int img = blockIdx.z, c0 = blockIdx.y * 64, p0 = (bx - d_cumS[lvl]) * 64;
  const float* s = src + ((size_t)img * 256 + c0) * HW + p0;
  const int tid = threadIdx.x;
#pragma unroll
  for (int i = 0; i < 4; i++) {
    const int cl = (tid >> 4) + i * 16, pl = (tid & 15) * 4;
    const float4 v = *(const float4*)(s + (size_t)cl * HW + pl);
    tile[cl][pl]     = f2bf(v.x);
    tile[cl][pl + 1] = f2bf(v.y);
    tile[cl][pl + 2] = f2bf(v.z);
    tile[cl][pl + 3] = f2bf(v.w);
  }
  __syncthreads();
  const int pl = tid >> 2, cseg = (tid & 3) * 16;
  unsigned ro[8];
#pragma unroll
  for (int k = 0; k < 8; k++)
    ro[k] = (unsigned)tile[cseg + 2 * k][pl] | ((unsigned)tile[cseg + 2 * k + 1][pl] << 16);
  const int ch0 = c0 + cseg;                      // multiple of 16
  char* db = (char*)dst + (size_t)img * TIB + (size_t)(ch0 >> 3) * XP
           + (size_t)(off + p0 + pl) * 16;
  uint4 u0 = {ro[0], ro[1], ro[2], ro[3]};
  uint4 u1 = {ro[4], ro[5], ro[6], ro[7]};
  *(uint4*)db = u0;
  *(uint4*)(db + XP) = u1;
}

// ---------------------------------------------------------------------------
// conv3x3 implicit GEMM, 3-buffer LDS ring, raw barrier + counted vmcnt.
// K-loop/staging R6-byte-exact. mode 0: tower conv -> plane-blocked Y (+bias).
// mode 1: output convs -> d_out.
__global__ __launch_bounds__(256) void conv_mfma(
    const unsigned short* __restrict__ xin0, const unsigned short* __restrict__ xin1,
    const unsigned short* __restrict__ wA, const unsigned short* __restrict__ wB,
    unsigned short* __restrict__ y0, unsigned short* __restrict__ y1,
    const float* __restrict__ cb0, const float* __restrict__ cb1,
    float* __restrict__ out,
    const float* __restrict__ ob_cls, const float* __restrict__ ob_reg, const float* __restrict__ ob_ctr,
    const unsigned short* __restrict__ zp, int mode) {
  __shared__ __align__(16) char smem[49152];   // 3 buffers x (A 8K | B 8K)
  const int tid = threadIdx.x;
  const int* cum = (mode == 0) ? d_cumT : d_cumO;
  const int nwg = (mode == 0) ? 1368 : 684;
  const int xcd = blockIdx.x & 7, cidx = blockIdx.x >> 3;
  const int qq = nwg >> 3, rr = nwg & 7;
  int bid = (xcd < rr ? xcd * (qq + 1) : rr * (qq + 1) + (xcd - rr) * qq) + cidx;
  int lvl = 0;
  while (bid >= cum[lvl + 1]) ++lvl;
  int r = bid - cum[lvl];
  const int lw = d_lw[lvl], W = 1 << lw, HW = 1 << (2 * lw), poffl = d_off[lvl];
  const int ntc = d_nt[lvl];
  const int nt = r % ntc; r /= ntc;
  int mt = 0;
  if (mode == 0) { mt = r & 1; r >>= 1; }
  const int img = r & 1, tower = r >> 1;

  const unsigned short* xin = (tower ? xin1 : xin0) + (size_t)img * 21824 * 256;
  const unsigned short* wset = tower ? wB : wA;

  const int n = tid & 127;
  const int p = nt * 128 + n;
  const bool pv = p < HW;
  const int h = p >> lw, w = p & (W - 1);
  const int kq = tid >> 7;

  const char* xb = (const char*)xin;
  const char* tb[9];
  int stp[9];
#pragma unroll
  for (int t = 0; t < 9; t++) {
    const int rr2 = h + t / 3 - 1, cx = w + t % 3 - 1;
    const bool v = pv && rr2 >= 0 && rr2 < W && cx >= 0 && cx < W;
    tb[t] = v ? xb + (size_t)kq * XP + (size_t)(poffl + rr2 * W + cx) * 16
              : (const char*)zp;
    stp[t] = v ? 4 * XP : 0;
  }

  const char* abase = (const char*)wset + (size_t)mt * 589824;
  const char* a_tid = abase + (size_t)tid * 16;
  char* l_tid = smem + tid * 16;

  const int lane = tid & 63, q = lane >> 4, lr = lane & 15;
  const int wv = tid >> 6, wm = wv >> 1, wn = wv & 1;
  int aoff[4], boff[4];
#pragma unroll
  for (int i = 0; i < 4; i++) {
    aoff[i] = ((q << 7) + wm * 64 + i * 16 + lr) << 4;
    boff[i] = (((q << 7) + wn * 64 + i * 16 + lr) << 4) + 8192;
  }

  floatx4 acc[4][4];
#pragma unroll
  for (int i = 0; i < 4; i++)
#pragma unroll
    for (int j = 0; j < 4; j++) acc[i][j] = (floatx4){0.f, 0.f, 0.f, 0.f};

#define UNIT(CC, U, WIMM)                                                     \
  {                                                                           \
    const int it_ = (CC) * 9 + (U);                                           \
    __builtin_amdgcn_s_waitcnt(WIMM);                                         \
    __builtin_amdgcn_s_barrier();                                             \
    asm volatile("" ::: "memory");                                            \
    if (it_ + 2 < 72) {                                                       \
      const int nu_ = (U) + 2;                                                \
      const int tn_ = nu_ % 9;            /* compile-time */                  \
      const int ccn_ = (CC) + nu_ / 9;                                        \
      char* la_ = l_tid + (nu_ % 3) * 16384;                                  \
      const char* ap_ = a_tid + (size_t)(it_ + 2) * 8192;                     \
      async16(ap_, la_);                                                      \
      async16(ap_ + 4096, la_ + 4096);                                        \
      const int sp_ = stp[tn_];                                               \
      const char* bp_ = tb[tn_] + ccn_ * sp_;                                 \
      async16(bp_, la_ + 8192);                                               \
      async16(bp_ + (sp_ >> 1), la_ + 12288);                                 \
    }                                                                         \
    asm volatile("" ::: "memory");                                            \
    const int sb_ = ((U) % 3) * 16384;                                        \
    short8 af[4], bfr[4];                                                     \
    _Pragma("unroll")                                                         \
    for (int i = 0; i < 4; i++) {                                             \
      af[i] = *(const short8*)(smem + sb_ + aoff[i]);                         \
      bfr[i] = *(const short8*)(smem + sb_ + boff[i]);                        \
    }                                                                         \
    _Pragma("unroll")                                                         \
    for (int i = 0; i < 4; i++)                                               \
      _Pragma("unroll")                                                       \
      for (int j = 0; j < 4; j++)                                             \
        acc[i][j] = __builtin_amdgcn_mfma_f32_16x16x32_bf16(af[i], bfr[j],    \
                                                            acc[i][j], 0, 0, 0); \
  }

  async16(a_tid, l_tid);
  async16(a_tid + 4096, l_tid + 4096);
  async16(tb[0], l_tid + 8192);
  async16(tb[0] + (stp[0] >> 1), l_tid + 12288);
  async16(a_tid + 8192, l_tid + 16384);
  async16(a_tid + 12288, l_tid + 20480);
  async16(tb[1], l_tid + 24576);
  async16(tb[1] + (stp[1] >> 1), l_tid + 28672);

  for (int cc = 0; cc < 7; ++cc) {
#pragma unroll
    for (int u = 0; u < 9; ++u) UNIT(cc, u, WAIT_VM4)
  }
  UNIT(7, 0, WAIT_VM4) UNIT(7, 1, WAIT_VM4) UNIT(7, 2, WAIT_VM4)
  UNIT(7, 3, WAIT_VM4) UNIT(7, 4, WAIT_VM4) UNIT(7, 5, WAIT_VM4)
  UNIT(7, 6, WAIT_VM4) UNIT(7, 7, WAIT_VM0) UNIT(7, 8, WAIT_VM0)
#undef UNIT

  if (mode == 0) {
    // plane-blocked Y write: uint2 at 16B stride; per wave-store, lanes cover
    // 2 planes x 16 consecutive slots = 4 cache lines (vs 64 for NHWC).
    char* yb = (char*)(tower ? y1 : y0) + (size_t)img * TIB;
    const float* cb = tower ? cb1 : cb0;
#pragma unroll
    for (int i = 0; i < 4; i++) {
      const int c = mt * 128 + wm * 64 + i * 16 + (q << 2);
      const float4 b4 = *(const float4*)(cb + c);
      char* yp = yb + (size_t)(c >> 3) * XP + (size_t)poffl * 16 + ((c & 7) << 1);
#pragma unroll
      for (int j = 0; j < 4; j++) {
        const int pp = nt * 128 + wn * 64 + j * 16 + lr;
        if (pp >= HW) continue;
        floatx4 a = acc[i][j];
        uint2 u;
        u.x = pk2(a.x + b4.x, a.y + b4.y);
        u.y = pk2(a.z + b4.z, a.w + b4.w);
        *(uint2*)(yp + (size_t)pp * 16) = u;
      }
    }
  } else {
#pragma unroll
    for (int j = 0; j < 4; j++) {
      const int pp = nt * 128 + wn * 64 + j * 16 + lr;
      if (pp >= HW) continue;
      const size_t gp = (size_t)poffl + pp;
#pragma unroll
      for (int i = 0; i < 4; i++) {
        const int m0 = wm * 64 + i * 16 + (q << 2);
        floatx4 a = acc[i][j];
#pragma unroll
        for (int k2 = 0; k2 < 4; k2++) {
          const int m = m0 + k2;
          const float v = a[k2];
          if (tower == 0) {
            if (m < 80) out[((size_t)img * 85 + m) * 21824 + gp] = v + ob_cls[m];
          } else {
            if (m < 4)
              out[((size_t)img * 85 + 80 + m) * 21824 + gp] = fmaxf(v + ob_reg[m], 0.f);
            else if (m == 4)
              out[((size_t)img * 85 + 84) * 21824 + gp] = v + ob_ctr[0];
          }
        }
      }
    }
  }
}

// ---------------------------------------------------------------------------
// GN stats over plane-blocked Y (R9-exact). Block = (chunk, group, tz).
// All threads reduce ONE group -> single atomicAdd pair per block.
__global__ __launch_bounds__(256) void gn_stats(
    const unsigned short* __restrict__ y0, const unsigned short* __restrict__ y1,
    float* __restrict__ stats) {
  const int ck = blockIdx.x, g = blockIdx.y, tz = blockIdx.z;
  const int tower = tz >> 1, img = tz & 1;
  const int lvl = ck_lvl[ck], c0 = ck_c0[ck], len = ck_len[ck];
  const char* base = (const char*)(tower ? y1 : y0) + (size_t)img * TIB
                   + (size_t)(2 * g) * XP + (size_t)(d_off[lvl] + c0) * 16;
  const int tid = threadIdx.x;
  float s = 0.f, s2 = 0.f;
  const int n2 = 2 * len;
  for (int i = tid; i < n2; i += 256) {
    const int pl = (i >= len);
    const int pos = i - pl * len;
    const uint4 d = *(const uint4*)(base + (size_t)pl * XP + (size_t)pos * 16);
    unsigned uu[4] = {d.x, d.y, d.z, d.w};
#pragma unroll
    for (int k = 0; k < 4; k++) {
      const float f0 = __uint_as_float(uu[k] << 16);
      const float f1 = __uint_as_float(uu[k] & 0xFFFF0000u);
      s += f0 + f1;
      s2 += f0 * f0 + f1 * f1;
    }
  }
#pragma unroll
  for (int m = 1; m < 64; m <<= 1) {
    s += __shfl_xor(s, m);
    s2 += __shfl_xor(s2, m);
  }
  __shared__ float rs[4], rq[4];
  const int lane = tid & 63, wvv = tid >> 6;
  if (lane == 0) { rs[wvv] = s; rq[wvv] = s2; }
  __syncthreads();
  if (tid == 0) {
    float* st = stats + (((tz * 5 + lvl) * 16 + g) << 1);
    atomicAdd(st, rs[0] + rs[1] + rs[2] + rs[3]);
    atomicAdd(st + 1, rq[0] + rq[1] + rq[2] + rq[3]);
  }
}

// ---------------------------------------------------------------------------
// GN apply + affine + ReLU + bf16: Y (plane) -> X (plane). Thread = one 16B
// slot. grid MUST be 10912 = 4 ti x 32 planes x 21824 pos / 256.
__global__ __launch_bounds__(256) void gn_apply(
    const unsigned short* __restrict__ ybase, unsigned short* __restrict__ xbase,
    const float* __restrict__ stats,
    const float* __restrict__ g0, const float* __restrict__ b0,
    const float* __restrict__ g1, const float* __restrict__ b1) {
  const int g = blockIdx.x * 256 + threadIdx.x;   // 0..2,793,471 exact
  const int pos = g % 21824;
  const int rest = g / 21824;                     // 0..127
  const int plane = rest & 31;
  const int ti = rest >> 5;                       // tower*2+img
  const int tower = ti >> 1;
  const int lvl = (pos >= 16384) + (pos >= 20480) + (pos >= 21504) + (pos >= 21760);
  const float cnt = (float)(16 << (2 * d_lw[lvl]));
  const float* st = stats + ((((ti * 5 + lvl) * 16 + (plane >> 1))) << 1);
  const float mean = st[0] / cnt;
  const float var = st[1] / cnt - mean * mean;
  const float rstd = rsqrtf(var + 1e-5f);
  const float* gam = (tower ? g1 : g0) + plane * 8;
  const float* bet = (tower ? b1 : b0) + plane * 8;
  const size_t off = (size_t)ti * TIB + (size_t)plane * XP + (size_t)pos * 16;
  const uint4 d = *(const uint4*)((const char*)ybase + off);
  unsigned uu[4] = {d.x, d.y, d.z, d.w};
  unsigned ro[4];
#pragma unroll
  for (int k = 0; k < 4; k++) {
    const float f0 = __uint_as_float(uu[k] << 16);
    const float f1 = __uint_as_float(uu[k] & 0xFFFF0000u);
    const float o0 = fmaxf((f0 - mean) * rstd * gam[2 * k] + bet[2 * k], 0.f);
    const float o1 = fmaxf((f1 - mean) * rstd * gam[2 * k + 1] + bet[2 * k + 1], 0.f);
    ro[k] = (unsigned)f2bf(o0) | ((unsigned)f2bf(o1) << 16);
  }
  uint4 od = {ro[0], ro[1], ro[2], ro[3]};
  *(uint4*)((char*)xbase + off) = od;
}

// ---------------------------------------------------------------------------
extern "C" void kernel_launch(void* const* d_in, const int* in_sizes, int n_in,
                              void* d_out, int out_size, void* d_ws, size_t ws_size,
                              hipStream_t stream) {
  (void)in_sizes; (void)n_in; (void)out_size; (void)ws_size;
  char* ws = (char*)d_ws;
  unsigned short* zp = (unsigned short*)ws;                 // 1536 B zeros
  unsigned short* wblk = (unsigned short*)(ws + 2048);      // 8,257,536 B
  const size_t WSET_T = 1179648;                            // bytes per tower set
  const size_t WSET_O = 589824;                             // bytes per out set
  char* pXfeat = ws + 2048 + 6 * WSET_T + 2 * WSET_O;
  const size_t XSZ = (size_t)2 * 21824 * 256 * 2;           // 22,347,776 B
  char* pX = pXfeat + XSZ;                                  // 2 towers
  char* pY = pX + 2 * XSZ;                                  // 2 towers
  float* stats = (float*)(pY + 2 * XSZ);                    // 3 stages x 640 floats

  // wtrans z==8 does the zero-page + stats init (zpk folded in)
  wtrans<<<dim3(2304, 9), 256, 0, stream>>>(
      (const float*)d_in[5], (const float*)d_in[9], (const float*)d_in[13],
      (const float*)d_in[17], (const float*)d_in[21], (const float*)d_in[25],
      (const float*)d_in[29], (const float*)d_in[31], (const float*)d_in[33],
      wblk, (float*)zp, stats);
  feat_nhwc<<<dim3(341, 4, 2), 256, 0, stream>>>(
      (const float*)d_in[0], (const float*)d_in[1], (const float*)d_in[2],
      (const float*)d_in[3], (const float*)d_in[4], (unsigned short*)pXfeat);

  unsigned short* xc = (unsigned short*)pX;
  unsigned short* xr = (unsigned short*)(pX + XSZ);
  unsigned short* yc = (unsigned short*)pY;
  unsigned short* yr = (unsigned short*)(pY + XSZ);

  for (int s = 0; s < 3; s++) {
    const unsigned short* in0 = s ? xc : (unsigned short*)pXfeat;
    const unsigned short* in1 = s ? xr : (unsigned short*)pXfeat;
    const unsigned short* wc = wblk + (size_t)s * 589824;        // elem stride per set
    const unsigned short* wr = wblk + (size_t)(3 + s) * 589824;
    float* st_s = stats + (size_t)s * 640;
    conv_mfma<<<1368, 256, 0, stream>>>(
        in0, in1, wc, wr, yc, yr,
        (const float*)d_in[6 + 4 * s], (const float*)d_in[18 + 4 * s],
        nullptr, nullptr, nullptr, nullptr, zp, 0);
    gn_stats<<<dim3(13, 16, 4), 256, 0, stream>>>(yc, yr, st_s);
    gn_apply<<<10912, 256, 0, stream>>>(
        (const unsigned short*)pY, (unsigned short*)pX, st_s,
        (const float*)d_in[7 + 4 * s], (const float*)d_in[8 + 4 * s],
        (const float*)d_in[19 + 4 * s], (const float*)d_in[20 + 4 * s]);
  }
  const unsigned short* wo_c = wblk + (size_t)6 * 589824;
  const unsigned short* wo_r = wo_c + 294912;
  conv_mfma<<<684, 256, 0, stream>>>(
      xc, xr, wo_c, wo_r, nullptr, nullptr, nullptr, nullptr,
      (float*)d_out, (const float*)d_in[30], (const float*)d_in[32],
      (const float*)d_in[34], zp, 1);
}

// Round 12
// 571.954 us; speedup vs baseline: 1.1222x; 1.0168x over previous
//
#include <hip/hip_runtime.h>
#include <stdint.h>

// FCOS head, MI355X. Implicit-GEMM conv3x3 via bf16 MFMA (16x16x32).
// Activations plane-blocked [plane=ch>>3][pos][16B] (XP stride) everywhere.
// R6: coalesced B staging (163->107 us). R9: plane Y + plane GN (600.6).
// R10 (and R1): residency (3 blk/CU) beats wave-tile width at this ring.
// R11: 581.5 us; conv 103.5 @ MfmaUtil 44.5.
// R11 re-analysis of R2/R3: conv epilogue stats fusion regressed because of
//   ATOMIC CONTENTION (22k device RMWs onto ~2 lines per level = ~106 us
//   serialization tail; MFMA/VALU busy-cycles were UNCHANGED), not codegen.
// R12: re-land stats fusion with PLAIN STORES -- each block owns partial slot
//   statsp[(tz*5+lvl)*16+g][nt] (shfl reduce + smem wn-combine, 0 atomics).
//   gn_stats deleted (-3 dispatches, -134 MB Y re-read). gn_apply re-gridded
//   (chunk,plane,ti) -- chunk=256pos aligns exactly with level boundaries --
//   with a per-block partial-reduction preamble. statsp zeroed in wtrans z=8.

typedef __attribute__((ext_vector_type(8))) short short8;
typedef __attribute__((ext_vector_type(4))) float floatx4;

#define XP 349184            // plane stride bytes = 21824 * 16
#define TIB (32 * XP)        // per (tower,img) block = 11,173,888 B

__device__ __forceinline__ unsigned short f2bf(float f) {
  unsigned u = __float_as_uint(f);
  u = (u + 0x7FFFu + ((u >> 16) & 1u)) >> 16;   // RNE
  return (unsigned short)u;
}
__device__ __forceinline__ unsigned pk2(float a, float b) {
  return (unsigned)f2bf(a) | ((unsigned)f2bf(b) << 16);
}
__device__ __forceinline__ void async16(const void* g, void* l) {
  __builtin_amdgcn_global_load_lds(
      (const __attribute__((address_space(1))) unsigned int*)g,
      (__attribute__((address_space(3))) unsigned int*)l, 16, 0, 0);
}

// s_waitcnt imm16 (gfx9 enc): vmcnt[3:0]|[15:14], expcnt[6:4], lgkmcnt[11:8]
#define WAIT_VM4 0x0F74   // vmcnt(4)
#define WAIT_VM0 0x0F70   // vmcnt(0)

// level geometry (fixed by problem): W = 1<<lw, HW = 1<<(2lw)
__device__ const int d_lw[5]   = {7, 6, 5, 4, 3};
__device__ const int d_off[5]  = {0, 16384, 20480, 21504, 21760};
__device__ const int d_nt[5]   = {128, 32, 8, 2, 1};           // ceil(HW/128)
__device__ const int d_cumT[6] = {0, 1024, 1280, 1344, 1360, 1368}; // 8*nt per level
__device__ const int d_cumO[6] = {0, 512, 640, 672, 680, 684};      // 4*nt per level
__device__ const int d_cumS[6] = {0, 256, 320, 336, 340, 341};      // HW/64 tiles

// ---------------------------------------------------------------------------
// weight transform: fp32 [O][I][3][3] -> bf16 blocked [mt][cc][tap][cs][m][8]
// z: 0..2 cls_w0..2, 3..5 reg_w0..2, 6 cls_out(pad 80->128), 7 reg_out+ctr
// z==8: blocks 0..79 zero statsp (81920 floats); block 80 zeros zero-page.
__global__ __launch_bounds__(256) void wtrans(
    const float* __restrict__ c0, const float* __restrict__ c1, const float* __restrict__ c2,
    const float* __restrict__ r0, const float* __restrict__ r1, const float* __restrict__ r2,
    const float* __restrict__ cw, const float* __restrict__ rw, const float* __restrict__ tw,
    unsigned short* __restrict__ dst, float* __restrict__ zp, float* __restrict__ statsp) {
  const int z = blockIdx.y;
  if (z == 8) {
    const int b = blockIdx.x;
    if (b < 80) {
      for (int k = threadIdx.x; k < 1024; k += 256) statsp[b * 1024 + k] = 0.f;
    } else if (b == 80) {
      for (int k = threadIdx.x; k < 384; k += 256) zp[k] = 0.f;
    }
    return;
  }
  const int nel = (z < 6) ? 589824 : 294912;
  const int idx = blockIdx.x * 256 + threadIdx.x;
  if (idx >= nel) return;
  int tmp = idx;
  const int j = tmp & 7;   tmp >>= 3;
  const int m = tmp & 127; tmp >>= 7;
  const int cs = tmp & 3;  tmp >>= 2;
  const int t = tmp % 9;   tmp /= 9;     // tap inner
  const int cc = tmp & 7;  const int mt = tmp >> 3;
  const int o = mt * 128 + m;
  const int i = cc * 32 + cs * 8 + j;
  float v = 0.f;
  const float* srcs[6] = {c0, c1, c2, r0, r1, r2};
  if (z < 6)      v = srcs[z][((size_t)o * 256 + i) * 9 + t];
  else if (z == 6){ if (o < 80) v = cw[((size_t)o * 256 + i) * 9 + t]; }
  else            { if (o < 4)  v = rw[((size_t)o * 256 + i) * 9 + t];
                    else if (o == 4) v = tw[(size_t)i * 9 + t]; }
  const size_t base = (z < 6) ? (size_t)z * 589824
                              : (size_t)6 * 589824 + (size_t)(z - 6) * 294912;
  dst[base + idx] = f2bf(v);
}

// ---------------------------------------------------------------------------
// feature NCHW fp32 -> plane-blocked bf16 (R6-exact).
__global__ __launch_bounds__(256) void feat_nhwc(
    const float* __restrict__ s0, const float* __restrict__ s1,
    const float* __restrict__ s2, const float* __restrict__ s3,
    const float* __restrict__ s4, unsigned short* __restrict__ dst) {
  __shared__ unsigned short tile[64][65];
  int bx = blockIdx.x, lvl = 0;
  while (bx >= d_cumS[lvl + 1]) ++lvl;
  const int HW = 1 << (2 * d_lw[lvl]), off = d_off[lvl];
  const float* srcs[5] = {s0, s1, s2, s3, s4};
  const float* src = srcs[lvl];
  const int img = blockIdx.z, c0 = blockIdx.y * 64, p0 = (bx - d_cumS[lvl]) * 64;
  const float* s = src + ((size_t)img * 256 + c0) * HW + p0;
  const int tid = threadIdx.x;
#pragma unroll
  for (int i = 0; i < 4; i++) {
    const int cl = (tid >> 4) + i * 16, pl = (tid & 15) * 4;
    const float4 v = *(const float4*)(s + (size_t)cl * HW + pl);
    tile[cl][pl]     = f2bf(v.x);
    tile[cl][pl + 1] = f2bf(v.y);
    tile[cl][pl + 2] = f2bf(v.z);
    tile[cl][pl + 3] = f2bf(v.w);
  }
  __syncthreads();
  const int pl = tid >> 2, cseg = (tid & 3) * 16;
  unsigned ro[8];
#pragma unroll
  for (int k = 0; k < 8; k++)
    ro[k] = (unsigned)tile[cseg + 2 * k][pl] | ((unsigned)tile[cseg + 2 * k + 1][pl] << 16);
  const int ch0 = c0 + cseg;                      // multiple of 16
  char* db = (char*)dst + (size_t)img * TIB + (size_t)(ch0 >> 3) * XP
           + (size_t)(off + p0 + pl) * 16;
  uint4 u0 = {ro[0], ro[1], ro[2], ro[3]};
  uint4 u1 = {ro[4], ro[5], ro[6], ro[7]};
  *(uint4*)db = u0;
  *(uint4*)(db + XP) = u1;
}

// ---------------------------------------------------------------------------
// conv3x3 implicit GEMM, 3-buffer LDS ring, raw barrier + counted vmcnt.
// K-loop/staging R6-byte-exact. mode 0: tower conv -> plane-blocked Y (+bias)
// + fused GN partials (plain stores, block-owned slots -- NO atomics).
// mode 1: output convs -> d_out.
__global__ __launch_bounds__(256) void conv_mfma(
    const unsigned short* __restrict__ xin0, const unsigned short* __restrict__ xin1,
    const unsigned short* __restrict__ wA, const unsigned short* __restrict__ wB,
    unsigned short* __restrict__ y0, unsigned short* __restrict__ y1,
    const float* __restrict__ cb0, const float* __restrict__ cb1,
    float* __restrict__ out,
    const float* __restrict__ ob_cls, const float* __restrict__ ob_reg, const float* __restrict__ ob_ctr,
    float* __restrict__ statsp, const unsigned short* __restrict__ zp, int mode) {
  __shared__ __align__(16) char smem[49152];   // 3 buffers x (A 8K | B 8K)
  const int tid = threadIdx.x;
  const int* cum = (mode == 0) ? d_cumT : d_cumO;
  const int nwg = (mode == 0) ? 1368 : 684;
  const int xcd = blockIdx.x & 7, cidx = blockIdx.x >> 3;
  const int qq = nwg >> 3, rr = nwg & 7;
  int bid = (xcd < rr ? xcd * (qq + 1) : rr * (qq + 1) + (xcd - rr) * qq) + cidx;
  int lvl = 0;
  while (bid >= cum[lvl + 1]) ++lvl;
  int r = bid - cum[lvl];
  const int lw = d_lw[lvl], W = 1 << lw, HW = 1 << (2 * lw), poffl = d_off[lvl];
  const int ntc = d_nt[lvl];
  const int nt = r % ntc; r /= ntc;
  int mt = 0;
  if (mode == 0) { mt = r & 1; r >>= 1; }
  const int img = r & 1, tower = r >> 1;

  const unsigned short* xin = (tower ? xin1 : xin0) + (size_t)img * 21824 * 256;
  const unsigned short* wset = tower ? wB : wA;

  const int n = tid & 127;
  const int p = nt * 128 + n;
  const bool pv = p < HW;
  const int h = p >> lw, w = p & (W - 1);
  const int kq = tid >> 7;

  const char* xb = (const char*)xin;
  const char* tb[9];
  int stp[9];
#pragma unroll
  for (int t = 0; t < 9; t++) {
    const int rr2 = h + t / 3 - 1, cx = w + t % 3 - 1;
    const bool v = pv && rr2 >= 0 && rr2 < W && cx >= 0 && cx < W;
    tb[t] = v ? xb + (size_t)kq * XP + (size_t)(poffl + rr2 * W + cx) * 16
              : (const char*)zp;
    stp[t] = v ? 4 * XP : 0;
  }

  const char* abase = (const char*)wset + (size_t)mt * 589824;
  const char* a_tid = abase + (size_t)tid * 16;
  char* l_tid = smem + tid * 16;

  const int lane = tid & 63, q = lane >> 4, lr = lane & 15;
  const int wv = tid >> 6, wm = wv >> 1, wn = wv & 1;
  int aoff[4], boff[4];
#pragma unroll
  for (int i = 0; i < 4; i++) {
    aoff[i] = ((q << 7) + wm * 64 + i * 16 + lr) << 4;
    boff[i] = (((q << 7) + wn * 64 + i * 16 + lr) << 4) + 8192;
  }

  floatx4 acc[4][4];
#pragma unroll
  for (int i = 0; i < 4; i++)
#pragma unroll
    for (int j = 0; j < 4; j++) acc[i][j] = (floatx4){0.f, 0.f, 0.f, 0.f};

#define UNIT(CC, U, WIMM)                                                     \
  {                                                                           \
    const int it_ = (CC) * 9 + (U);                                           \
    __builtin_amdgcn_s_waitcnt(WIMM);                                         \
    __builtin_amdgcn_s_barrier();                                             \
    asm volatile("" ::: "memory");                                            \
    if (it_ + 2 < 72) {                                                       \
      const int nu_ = (U) + 2;                                                \
      const int tn_ = nu_ % 9;            /* compile-time */                  \
      const int ccn_ = (CC) + nu_ / 9;                                        \
      char* la_ = l_tid + (nu_ % 3) * 16384;                                  \
      const char* ap_ = a_tid + (size_t)(it_ + 2) * 8192;                     \
      async16(ap_, la_);                                                      \
      async16(ap_ + 4096, la_ + 4096);                                        \
      const int sp_ = stp[tn_];                                               \
      const char* bp_ = tb[tn_] + ccn_ * sp_;                                 \
      async16(bp_, la_ + 8192);                                               \
      async16(bp_ + (sp_ >> 1), la_ + 12288);                                 \
    }                                                                         \
    asm volatile("" ::: "memory");                                            \
    const int sb_ = ((U) % 3) * 16384;                                        \
    short8 af[4], bfr[4];                                                     \
    _Pragma("unroll")                                                         \
    for (int i = 0; i < 4; i++) {                                             \
      af[i] = *(const short8*)(smem + sb_ + aoff[i]);                         \
      bfr[i] = *(const short8*)(smem + sb_ + boff[i]);                        \
    }                                                                         \
    _Pragma("unroll")                                                         \
    for (int i = 0; i < 4; i++)                                               \
      _Pragma("unroll")                                                       \
      for (int j = 0; j < 4; j++)                                             \
        acc[i][j] = __builtin_amdgcn_mfma_f32_16x16x32_bf16(af[i], bfr[j],    \
                                                            acc[i][j], 0, 0, 0); \
  }

  async16(a_tid, l_tid);
  async16(a_tid + 4096, l_tid + 4096);
  async16(tb[0], l_tid + 8192);
  async16(tb[0] + (stp[0] >> 1), l_tid + 12288);
  async16(a_tid + 8192, l_tid + 16384);
  async16(a_tid + 12288, l_tid + 20480);
  async16(tb[1], l_tid + 24576);
  async16(tb[1] + (stp[1] >> 1), l_tid + 28672);

  for (int cc = 0; cc < 7; ++cc) {
#pragma unroll
    for (int u = 0; u < 9; ++u) UNIT(cc, u, WAIT_VM4)
  }
  UNIT(7, 0, WAIT_VM4) UNIT(7, 1, WAIT_VM4) UNIT(7, 2, WAIT_VM4)
  UNIT(7, 3, WAIT_VM4) UNIT(7, 4, WAIT_VM4) UNIT(7, 5, WAIT_VM4)
  UNIT(7, 6, WAIT_VM4) UNIT(7, 7, WAIT_VM0) UNIT(7, 8, WAIT_VM0)
#undef UNIT

  if (mode == 0) {
    // plane-blocked Y write (+bias), accumulating GN partial sums
    char* yb = (char*)(tower ? y1 : y0) + (size_t)img * TIB;
    const float* cb = tower ? cb1 : cb0;
    float sv[4] = {0.f, 0.f, 0.f, 0.f}, sq[4] = {0.f, 0.f, 0.f, 0.f};
#pragma unroll
    for (int i = 0; i < 4; i++) {
      const int c = mt * 128 + wm * 64 + i * 16 + (q << 2);
      const float4 b4 = *(const float4*)(cb + c);
      char* yp = yb + (size_t)(c >> 3) * XP + (size_t)poffl * 16 + ((c & 7) << 1);
#pragma unroll
      for (int j = 0; j < 4; j++) {
        const int pp = nt * 128 + wn * 64 + j * 16 + lr;
        if (pp >= HW) continue;
        floatx4 a = acc[i][j];
        const float v0 = a.x + b4.x, v1 = a.y + b4.y;
        const float v2 = a.z + b4.z, v3 = a.w + b4.w;
        uint2 u;
        u.x = pk2(v0, v1);
        u.y = pk2(v2, v3);
        *(uint2*)(yp + (size_t)pp * 16) = u;
        sv[i] += v0 + v1 + v2 + v3;
        sq[i] += v0 * v0 + v1 * v1 + v2 * v2 + v3 * v3;
      }
    }
    // fused GN partials: wave shfl-reduce, cross-wn combine via dead smem,
    // then PLAIN stores to the block-owned slot (no atomics -- R2's tail).
    float* smf = (float*)smem;
    __syncthreads();                 // all waves finished K-loop smem reads
#pragma unroll
    for (int i = 0; i < 4; i++) {
      float S = sv[i], Q = sq[i];
#pragma unroll
      for (int m2 = 1; m2 < 64; m2 <<= 1) {
        S += __shfl_xor(S, m2);
        Q += __shfl_xor(Q, m2);
      }
      if (lane == 0) { smf[wv * 8 + i * 2] = S; smf[wv * 8 + i * 2 + 1] = Q; }
    }
    __syncthreads();
    if (wn == 0 && lane == 0) {
      const int tz = tower * 2 + img;
#pragma unroll
      for (int i = 0; i < 4; i++) {
        const int gidx = mt * 8 + wm * 4 + i;
        const float S = smf[wv * 8 + i * 2] + smf[(wv + 1) * 8 + i * 2];
        const float Q = smf[wv * 8 + i * 2 + 1] + smf[(wv + 1) * 8 + i * 2 + 1];
        float* dst2 = statsp + (size_t)(((tz * 5 + lvl) * 16 + gidx) * 128 + nt) * 2;
        dst2[0] = S;
        dst2[1] = Q;
      }
    }
  } else {
#pragma unroll
    for (int j = 0; j < 4; j++) {
      const int pp = nt * 128 + wn * 64 + j * 16 + lr;
      if (pp >= HW) continue;
      const size_t gp = (size_t)poffl + pp;
#pragma unroll
      for (int i = 0; i < 4; i++) {
        const int m0 = wm * 64 + i * 16 + (q << 2);
        floatx4 a = acc[i][j];
#pragma unroll
        for (int k2 = 0; k2 < 4; k2++) {
          const int m = m0 + k2;
          const float v = a[k2];
          if (tower == 0) {
            if (m < 80) out[((size_t)img * 85 + m) * 21824 + gp] = v + ob_cls[m];
          } else {
            if (m < 4)
              out[((size_t)img * 85 + 80 + m) * 21824 + gp] = fmaxf(v + ob_reg[m], 0.f);
            else if (m == 4)
              out[((size_t)img * 85 + 84) * 21824 + gp] = v + ob_ctr[0];
          }
        }
      }
    }
  }
}

// ---------------------------------------------------------------------------
// GN apply + affine + ReLU + bf16: Y (plane) -> X (plane).
// Grid (chunk 86, plane 32, ti 4); chunk = 256 consecutive pos. Level
// boundaries (16384/20480/21504/21760) are all multiples of 256, so every
// block is single-(ti,lvl,group). Preamble reduces the <=128 conv partials.
__global__ __launch_bounds__(256) void gn_apply(
    const unsigned short* __restrict__ ybase, unsigned short* __restrict__ xbase,
    const float* __restrict__ statsp,
    const float* __restrict__ g0, const float* __restrict__ b0,
    const float* __restrict__ g1, const float* __restrict__ b1) {
  const int chunk = blockIdx.x;        // 0..85
  const int plane = blockIdx.y;        // 0..31
  const int ti = blockIdx.z;           // tower*2+img
  const int tid = threadIdx.x;
  const int lvl = (chunk >= 64) + (chunk >= 80) + (chunk >= 84) + (chunk >= 85);
  const int ntc = d_nt[lvl];
  const int g = plane >> 1;
  const float* sp = statsp + (size_t)(((ti * 5 + lvl) * 16 + g) * 128) * 2;
  float S = 0.f, Q = 0.f;
  if (tid < ntc) { S = sp[2 * tid]; Q = sp[2 * tid + 1]; }
#pragma unroll
  for (int m = 1; m < 64; m <<= 1) {
    S += __shfl_xor(S, m);
    Q += __shfl_xor(Q, m);
  }
  __shared__ float red[2][2];
  if (tid == 0 || tid == 64) { red[tid >> 6][0] = S; red[tid >> 6][1] = Q; }
  __syncthreads();
  const float St = red[0][0] + red[1][0];
  const float Qt = red[0][1] + red[1][1];
  const float cnt = (float)(16 << (2 * d_lw[lvl]));
  const float mean = St / cnt;
  const float var = Qt / cnt - mean * mean;
  const float rstd = rsqrtf(var + 1e-5f);

  const int pos = chunk * 256 + tid;
  if (pos >= 21824) return;            // only chunk 85 tail
  const int tower = ti >> 1;
  const float* gam = (tower ? g1 : g0) + plane * 8;
  const float* bet = (tower ? b1 : b0) + plane * 8;
  const size_t off = (size_t)ti * TIB + (size_t)plane * XP + (size_t)pos * 16;
  const uint4 d = *(const uint4*)((const char*)ybase + off);
  unsigned uu[4] = {d.x, d.y, d.z, d.w};
  unsigned ro[4];
#pragma unroll
  for (int k = 0; k < 4; k++) {
    const float f0 = __uint_as_float(uu[k] << 16);
    const float f1 = __uint_as_float(uu[k] & 0xFFFF0000u);
    const float o0 = fmaxf((f0 - mean) * rstd * gam[2 * k] + bet[2 * k], 0.f);
    const float o1 = fmaxf((f1 - mean) * rstd * gam[2 * k + 1] + bet[2 * k + 1], 0.f);
    ro[k] = (unsigned)f2bf(o0) | ((unsigned)f2bf(o1) << 16);
  }
  uint4 od = {ro[0], ro[1], ro[2], ro[3]};
  *(uint4*)((char*)xbase + off) = od;
}

// ---------------------------------------------------------------------------
extern "C" void kernel_launch(void* const* d_in, const int* in_sizes, int n_in,
                              void* d_out, int out_size, void* d_ws, size_t ws_size,
                              hipStream_t stream) {
  (void)in_sizes; (void)n_in; (void)out_size; (void)ws_size;
  char* ws = (char*)d_ws;
  unsigned short* zp = (unsigned short*)ws;                 // 1536 B zeros
  unsigned short* wblk = (unsigned short*)(ws + 2048);      // 8,257,536 B
  const size_t WSET_T = 1179648;                            // bytes per tower set
  const size_t WSET_O = 589824;                             // bytes per out set
  char* pXfeat = ws + 2048 + 6 * WSET_T + 2 * WSET_O;
  const size_t XSZ = (size_t)2 * 21824 * 256 * 2;           // 22,347,776 B
  char* pX = pXfeat + XSZ;                                  // 2 towers
  char* pY = pX + 2 * XSZ;                                  // 2 towers
  float* statsp = (float*)(pY + 2 * XSZ);                   // 81920 floats partials

  // wtrans z==8: zero statsp (blocks 0..79) + zero page (block 80)
  wtrans<<<dim3(2304, 9), 256, 0, stream>>>(
      (const float*)d_in[5], (const float*)d_in[9], (const float*)d_in[13],
      (const float*)d_in[17], (const float*)d_in[21], (const float*)d_in[25],
      (const float*)d_in[29], (const float*)d_in[31], (const float*)d_in[33],
      wblk, (float*)zp, statsp);
  feat_nhwc<<<dim3(341, 4, 2), 256, 0, stream>>>(
      (const float*)d_in[0], (const float*)d_in[1], (const float*)d_in[2],
      (const float*)d_in[3], (const float*)d_in[4], (unsigned short*)pXfeat);

  unsigned short* xc = (unsigned short*)pX;
  unsigned short* xr = (unsigned short*)(pX + XSZ);
  unsigned short* yc = (unsigned short*)pY;
  unsigned short* yr = (unsigned short*)(pY + XSZ);

  for (int s = 0; s < 3; s++) {
    const unsigned short* in0 = s ? xc : (unsigned short*)pXfeat;
    const unsigned short* in1 = s ? xr : (unsigned short*)pXfeat;
    const unsigned short* wc = wblk + (size_t)s * 589824;        // elem stride per set
    const unsigned short* wr = wblk + (size_t)(3 + s) * 589824;
    conv_mfma<<<1368, 256, 0, stream>>>(
        in0, in1, wc, wr, yc, yr,
        (const float*)d_in[6 + 4 * s], (const float*)d_in[18 + 4 * s],
        nullptr, nullptr, nullptr, nullptr, statsp, zp, 0);
    gn_apply<<<dim3(86, 32, 4), 256, 0, stream>>>(
        (const unsigned short*)pY, (unsigned short*)pX, statsp,
        (const float*)d_in[7 + 4 * s], (const float*)d_in[8 + 4 * s],
        (const float*)d_in[19 + 4 * s], (const float*)d_in[20 + 4 * s]);
  }
  const unsigned short* wo_c = wblk + (size_t)6 * 589824;
  const unsigned short* wo_r = wo_c + 294912;
  conv_mfma<<<684, 256, 0, stream>>>(
      xc, xr, wo_c, wo_r, nullptr, nullptr, nullptr, nullptr,
      (float*)d_out, (const float*)d_in[30], (const float*)d_in[32],
      (const float*)d_in[34], nullptr, zp, 1);
}

// Round 13
// 565.585 us; speedup vs baseline: 1.1349x; 1.0113x over previous
//
#include <hip/hip_runtime.h>
#include <stdint.h>

// FCOS head, MI355X. Implicit-GEMM conv3x3 via bf16 MFMA (16x16x32).
// Activations plane-blocked [plane=ch>>3][pos][16B] (XP stride) everywhere.
// R6: coalesced B staging (163->107 us). R9: plane Y + plane GN (600.6).
// R10 (and R1): residency (3 blk/CU) beats wave-tile width at this ring.
// R12: GN stats fused into conv epilogue with plain stores (no atomics --
//   R2/R3's regression was atomic contention, ~106 us serialization tail);
//   571.95 us, conv 111.4 (K-loop time conserved: MfmaUtil x dur const).
// R13: (a) epilogue diet -- drop both syncthreads + smem combine; each wave
//   stores its own partial to slot [combo*256 + nt*2 + wn]; gn_apply reduces
//   <=256 partials. No statsp zeroing needed (every read slot is written).
//   (b) wtrans + feat_nhwc merged into one dispatch (prep): latency-bound
//   strided weight gather overlaps BW-bound feature transpose.

typedef __attribute__((ext_vector_type(8))) short short8;
typedef __attribute__((ext_vector_type(4))) float floatx4;

#define XP 349184            // plane stride bytes = 21824 * 16
#define TIB (32 * XP)        // per (tower,img) block = 11,173,888 B

__device__ __forceinline__ unsigned short f2bf(float f) {
  unsigned u = __float_as_uint(f);
  u = (u + 0x7FFFu + ((u >> 16) & 1u)) >> 16;   // RNE
  return (unsigned short)u;
}
__device__ __forceinline__ unsigned pk2(float a, float b) {
  return (unsigned)f2bf(a) | ((unsigned)f2bf(b) << 16);
}
__device__ __forceinline__ void async16(const void* g, void* l) {
  __builtin_amdgcn_global_load_lds(
      (const __attribute__((address_space(1))) unsigned int*)g,
      (__attribute__((address_space(3))) unsigned int*)l, 16, 0, 0);
}

// s_waitcnt imm16 (gfx9 enc): vmcnt[3:0]|[15:14], expcnt[6:4], lgkmcnt[11:8]
#define WAIT_VM4 0x0F74   // vmcnt(4)
#define WAIT_VM0 0x0F70   // vmcnt(0)

// level geometry (fixed by problem): W = 1<<lw, HW = 1<<(2lw)
__device__ const int d_lw[5]   = {7, 6, 5, 4, 3};
__device__ const int d_off[5]  = {0, 16384, 20480, 21504, 21760};
__device__ const int d_nt[5]   = {128, 32, 8, 2, 1};           // ceil(HW/128)
__device__ const int d_cumT[6] = {0, 1024, 1280, 1344, 1360, 1368}; // 8*nt per level
__device__ const int d_cumO[6] = {0, 512, 640, 672, 680, 684};      // 4*nt per level
__device__ const int d_cumS[6] = {0, 256, 320, 336, 340, 341};      // HW/64 tiles

// ---------------------------------------------------------------------------
// prep: merged weight transform + feature layout + zero-page init.
// y 0..7: wtrans z=y (fp32 [O][I][3][3] -> bf16 blocked [mt][cc][tap][cs][m][8];
//   z 0..2 cls_w0..2, 3..5 reg_w0..2, 6 cls_out pad80->128, 7 reg_out+ctr pad).
// y==8: feat block fid = bx; y==9: bx<424 -> fid = 2304+bx (2728 total);
//   bx==424 -> zero page init.
__global__ __launch_bounds__(256) void prep(
    const float* __restrict__ c0, const float* __restrict__ c1, const float* __restrict__ c2,
    const float* __restrict__ r0, const float* __restrict__ r1, const float* __restrict__ r2,
    const float* __restrict__ cw, const float* __restrict__ rw, const float* __restrict__ tw,
    unsigned short* __restrict__ dst, float* __restrict__ zp,
    const float* __restrict__ s0, const float* __restrict__ s1,
    const float* __restrict__ s2, const float* __restrict__ s3,
    const float* __restrict__ s4, unsigned short* __restrict__ fdst) {
  __shared__ unsigned short tile[64][65];
  const int z = blockIdx.y;
  const int tid = threadIdx.x;
  if (z < 8) {
    const int nel = (z < 6) ? 589824 : 294912;
    const int idx = blockIdx.x * 256 + tid;
    if (idx >= nel) return;
    int tmp = idx;
    const int j = tmp & 7;   tmp >>= 3;
    const int m = tmp & 127; tmp >>= 7;
    const int cs = tmp & 3;  tmp >>= 2;
    const int t = tmp % 9;   tmp /= 9;     // tap inner
    const int cc = tmp & 7;  const int mt = tmp >> 3;
    const int o = mt * 128 + m;
    const int i = cc * 32 + cs * 8 + j;
    float v = 0.f;
    const float* srcs[6] = {c0, c1, c2, r0, r1, r2};
    if (z < 6)      v = srcs[z][((size_t)o * 256 + i) * 9 + t];
    else if (z == 6){ if (o < 80) v = cw[((size_t)o * 256 + i) * 9 + t]; }
    else            { if (o < 4)  v = rw[((size_t)o * 256 + i) * 9 + t];
                      else if (o == 4) v = tw[(size_t)i * 9 + t]; }
    const size_t base = (z < 6) ? (size_t)z * 589824
                                : (size_t)6 * 589824 + (size_t)(z - 6) * 294912;
    dst[base + idx] = f2bf(v);
    return;
  }
  // y==8 / y==9: feature transpose (or zp init)
  int fid;
  if (z == 8) {
    fid = blockIdx.x;
  } else {
    if (blockIdx.x < 424) fid = 2304 + blockIdx.x;
    else if (blockIdx.x == 424) {
      for (int k = tid; k < 384; k += 256) zp[k] = 0.f;
      return;
    } else return;
  }
  const int bx0 = fid % 341;
  const int tq = fid / 341;          // 0..7
  const int qy = tq & 3, img = tq >> 2;
  int bx = bx0, lvl = 0;
  while (bx >= d_cumS[lvl + 1]) ++lvl;
  const int HW = 1 << (2 * d_lw[lvl]), off = d_off[lvl];
  const float* srcs[5] = {s0, s1, s2, s3, s4};
  const float* src = srcs[lvl];
  const int cch0 = qy * 64, p0 = (bx - d_cumS[lvl]) * 64;
  const float* s = src + ((size_t)img * 256 + cch0) * HW + p0;
#pragma unroll
  for (int i = 0; i < 4; i++) {
    const int cl = (tid >> 4) + i * 16, pl = (tid & 15) * 4;
    const float4 v = *(const float4*)(s + (size_t)cl * HW + pl);
    tile[cl][pl]     = f2bf(v.x);
    tile[cl][pl + 1] = f2bf(v.y);
    tile[cl][pl + 2] = f2bf(v.z);
    tile[cl][pl + 3] = f2bf(v.w);
  }
  __syncthreads();
  const int pl = tid >> 2, cseg = (tid & 3) * 16;
  unsigned ro[8];
#pragma unroll
  for (int k = 0; k < 8; k++)
    ro[k] = (unsigned)tile[cseg + 2 * k][pl] | ((unsigned)tile[cseg + 2 * k + 1][pl] << 16);
  const int ch0 = cch0 + cseg;                    // multiple of 16
  char* db = (char*)fdst + (size_t)img * TIB + (size_t)(ch0 >> 3) * XP
           + (size_t)(off + p0 + pl) * 16;
  uint4 u0 = {ro[0], ro[1], ro[2], ro[3]};
  uint4 u1 = {ro[4], ro[5], ro[6], ro[7]};
  *(uint4*)db = u0;
  *(uint4*)(db + XP) = u1;
}

// ---------------------------------------------------------------------------
// conv3x3 implicit GEMM, 3-buffer LDS ring, raw barrier + counted vmcnt.
// K-loop/staging R6-byte-exact. mode 0: tower conv -> plane-blocked Y (+bias)
// + fused GN partials (per-wave plain store, wave-owned slot, no barriers).
// mode 1: output convs -> d_out.
__global__ __launch_bounds__(256) void conv_mfma(
    const unsigned short* __restrict__ xin0, const unsigned short* __restrict__ xin1,
    const unsigned short* __restrict__ wA, const unsigned short* __restrict__ wB,
    unsigned short* __restrict__ y0, unsigned short* __restrict__ y1,
    const float* __restrict__ cb0, const float* __restrict__ cb1,
    float* __restrict__ out,
    const float* __restrict__ ob_cls, const float* __restrict__ ob_reg, const float* __restrict__ ob_ctr,
    float* __restrict__ statsp, const unsigned short* __restrict__ zp, int mode) {
  __shared__ __align__(16) char smem[49152];   // 3 buffers x (A 8K | B 8K)
  const int tid = threadIdx.x;
  const int* cum = (mode == 0) ? d_cumT : d_cumO;
  const int nwg = (mode == 0) ? 1368 : 684;
  const int xcd = blockIdx.x & 7, cidx = blockIdx.x >> 3;
  const int qq = nwg >> 3, rr = nwg & 7;
  int bid = (xcd < rr ? xcd * (qq + 1) : rr * (qq + 1) + (xcd - rr) * qq) + cidx;
  int lvl = 0;
  while (bid >= cum[lvl + 1]) ++lvl;
  int r = bid - cum[lvl];
  const int lw = d_lw[lvl], W = 1 << lw, HW = 1 << (2 * lw), poffl = d_off[lvl];
  const int ntc = d_nt[lvl];
  const int nt = r % ntc; r /= ntc;
  int mt = 0;
  if (mode == 0) { mt = r & 1; r >>= 1; }
  const int img = r & 1, tower = r >> 1;

  const unsigned short* xin = (tower ? xin1 : xin0) + (size_t)img * 21824 * 256;
  const unsigned short* wset = tower ? wB : wA;

  const int n = tid & 127;
  const int p = nt * 128 + n;
  const bool pv = p < HW;
  const int h = p >> lw, w = p & (W - 1);
  const int kq = tid >> 7;

  const char* xb = (const char*)xin;
  const char* tb[9];
  int stp[9];
#pragma unroll
  for (int t = 0; t < 9; t++) {
    const int rr2 = h + t / 3 - 1, cx = w + t % 3 - 1;
    const bool v = pv && rr2 >= 0 && rr2 < W && cx >= 0 && cx < W;
    tb[t] = v ? xb + (size_t)kq * XP + (size_t)(poffl + rr2 * W + cx) * 16
              : (const char*)zp;
    stp[t] = v ? 4 * XP : 0;
  }

  const char* abase = (const char*)wset + (size_t)mt * 589824;
  const char* a_tid = abase + (size_t)tid * 16;
  char* l_tid = smem + tid * 16;

  const int lane = tid & 63, q = lane >> 4, lr = lane & 15;
  const int wv = tid >> 6, wm = wv >> 1, wn = wv & 1;
  int aoff[4], boff[4];
#pragma unroll
  for (int i = 0; i < 4; i++) {
    aoff[i] = ((q << 7) + wm * 64 + i * 16 + lr) << 4;
    boff[i] = (((q << 7) + wn * 64 + i * 16 + lr) << 4) + 8192;
  }

  floatx4 acc[4][4];
#pragma unroll
  for (int i = 0; i < 4; i++)
#pragma unroll
    for (int j = 0; j < 4; j++) acc[i][j] = (floatx4){0.f, 0.f, 0.f, 0.f};

#define UNIT(CC, U, WIMM)                                                     \
  {                                                                           \
    const int it_ = (CC) * 9 + (U);                                           \
    __builtin_amdgcn_s_waitcnt(WIMM);                                         \
    __builtin_amdgcn_s_barrier();                                             \
    asm volatile("" ::: "memory");                                            \
    if (it_ + 2 < 72) {                                                       \
      const int nu_ = (U) + 2;                                                \
      const int tn_ = nu_ % 9;            /* compile-time */                  \
      const int ccn_ = (CC) + nu_ / 9;                                        \
      char* la_ = l_tid + (nu_ % 3) * 16384;                                  \
      const char* ap_ = a_tid + (size_t)(it_ + 2) * 8192;                     \
      async16(ap_, la_);                                                      \
      async16(ap_ + 4096, la_ + 4096);                                        \
      const int sp_ = stp[tn_];                                               \
      const char* bp_ = tb[tn_] + ccn_ * sp_;                                 \
      async16(bp_, la_ + 8192);                                               \
      async16(bp_ + (sp_ >> 1), la_ + 12288);                                 \
    }                                                                         \
    asm volatile("" ::: "memory");                                            \
    const int sb_ = ((U) % 3) * 16384;                                        \
    short8 af[4], bfr[4];                                                     \
    _Pragma("unroll")                                                         \
    for (int i = 0; i < 4; i++) {                                             \
      af[i] = *(const short8*)(smem + sb_ + aoff[i]);                         \
      bfr[i] = *(const short8*)(smem + sb_ + boff[i]);                        \
    }                                                                         \
    _Pragma("unroll")                                                         \
    for (int i = 0; i < 4; i++)                                               \
      _Pragma("unroll")                                                       \
      for (int j = 0; j < 4; j++)                                             \
        acc[i][j] = __builtin_amdgcn_mfma_f32_16x16x32_bf16(af[i], bfr[j],    \
                                                            acc[i][j], 0, 0, 0); \
  }

  async16(a_tid, l_tid);
  async16(a_tid + 4096, l_tid + 4096);
  async16(tb[0], l_tid + 8192);
  async16(tb[0] + (stp[0] >> 1), l_tid + 12288);
  async16(a_tid + 8192, l_tid + 16384);
  async16(a_tid + 12288, l_tid + 20480);
  async16(tb[1], l_tid + 24576);
  async16(tb[1] + (stp[1] >> 1), l_tid + 28672);

  for (int cc = 0; cc < 7; ++cc) {
#pragma unroll
    for (int u = 0; u < 9; ++u) UNIT(cc, u, WAIT_VM4)
  }
  UNIT(7, 0, WAIT_VM4) UNIT(7, 1, WAIT_VM4) UNIT(7, 2, WAIT_VM4)
  UNIT(7, 3, WAIT_VM4) UNIT(7, 4, WAIT_VM4) UNIT(7, 5, WAIT_VM4)
  UNIT(7, 6, WAIT_VM4) UNIT(7, 7, WAIT_VM0) UNIT(7, 8, WAIT_VM0)
#undef UNIT

  if (mode == 0) {
    // plane-blocked Y write (+bias), accumulating GN partial sums
    char* yb = (char*)(tower ? y1 : y0) + (size_t)img * TIB;
    const float* cb = tower ? cb1 : cb0;
    float sv[4] = {0.f, 0.f, 0.f, 0.f}, sq[4] = {0.f, 0.f, 0.f, 0.f};
#pragma unroll
    for (int i = 0; i < 4; i++) {
      const int c = mt * 128 + wm * 64 + i * 16 + (q << 2);
      const float4 b4 = *(const float4*)(cb + c);
      char* yp = yb + (size_t)(c >> 3) * XP + (size_t)poffl * 16 + ((c & 7) << 1);
#pragma unroll
      for (int j = 0; j < 4; j++) {
        const int pp = nt * 128 + wn * 64 + j * 16 + lr;
        if (pp >= HW) continue;
        floatx4 a = acc[i][j];
        const float v0 = a.x + b4.x, v1 = a.y + b4.y;
        const float v2 = a.z + b4.z, v3 = a.w + b4.w;
        uint2 u;
        u.x = pk2(v0, v1);
        u.y = pk2(v2, v3);
        *(uint2*)(yp + (size_t)pp * 16) = u;
        sv[i] += v0 + v1 + v2 + v3;
        sq[i] += v0 * v0 + v1 * v1 + v2 * v2 + v3 * v3;
      }
    }
    // fused GN partials: per-wave shfl reduce, plain store to wave-owned slot
    // [combo*256 + nt*2 + wn] -- no barriers, no smem, no atomics. Every slot
    // gn_apply reads (2*ntc per group) is written here, so no zeroing needed.
    const int tz = tower * 2 + img;
#pragma unroll
    for (int i = 0; i < 4; i++) {
      float S = sv[i], Q = sq[i];
#pragma unroll
      for (int m2 = 1; m2 < 64; m2 <<= 1) {
        S += __shfl_xor(S, m2);
        Q += __shfl_xor(Q, m2);
      }
      if (lane == 0) {
        const int gidx = mt * 8 + wm * 4 + i;
        float* dst2 = statsp +
            (size_t)((((tz * 5 + lvl) * 16 + gidx) * 256) + nt * 2 + wn) * 2;
        dst2[0] = S;
        dst2[1] = Q;
      }
    }
  } else {
#pragma unroll
    for (int j = 0; j < 4; j++) {
      const int pp = nt * 128 + wn * 64 + j * 16 + lr;
      if (pp >= HW) continue;
      const size_t gp = (size_t)poffl + pp;
#pragma unroll
      for (int i = 0; i < 4; i++) {
        const int m0 = wm * 64 + i * 16 + (q << 2);
        floatx4 a = acc[i][j];
#pragma unroll
        for (int k2 = 0; k2 < 4; k2++) {
          const int m = m0 + k2;
          const float v = a[k2];
          if (tower == 0) {
            if (m < 80) out[((size_t)img * 85 + m) * 21824 + gp] = v + ob_cls[m];
          } else {
            if (m < 4)
              out[((size_t)img * 85 + 80 + m) * 21824 + gp] = fmaxf(v + ob_reg[m], 0.f);
            else if (m == 4)
              out[((size_t)img * 85 + 84) * 21824 + gp] = v + ob_ctr[0];
          }
        }
      }
    }
  }
}

// ---------------------------------------------------------------------------
// GN apply + affine + ReLU + bf16: Y (plane) -> X (plane).
// Grid (chunk 86, plane 32, ti 4); chunk = 256 consecutive pos (level
// boundaries are all x256). Preamble reduces the <=256 per-wave conv
// partials (slots 0..2*ntc-1) with a 4-wave block reduce.
__global__ __launch_bounds__(256) void gn_apply(
    const unsigned short* __restrict__ ybase, unsigned short* __restrict__ xbase,
    const float* __restrict__ statsp,
    const float* __restrict__ g0, const float* __restrict__ b0,
    const float* __restrict__ g1, const float* __restrict__ b1) {
  const int chunk = blockIdx.x;        // 0..85
  const int plane = blockIdx.y;        // 0..31
  const int ti = blockIdx.z;           // tower*2+img
  const int tid = threadIdx.x;
  const int lvl = (chunk >= 64) + (chunk >= 80) + (chunk >= 84) + (chunk >= 85);
  const int ntc2 = 2 * d_nt[lvl];      // 256,64,16,4,2
  const int g = plane >> 1;
  const float* sp = statsp + (size_t)(((ti * 5 + lvl) * 16 + g) * 256) * 2;
  float S = 0.f, Q = 0.f;
  if (tid < ntc2) { S = sp[2 * tid]; Q = sp[2 * tid + 1]; }
#pragma unroll
  for (int m = 1; m < 64; m <<= 1) {
    S += __shfl_xor(S, m);
    Q += __shfl_xor(Q, m);
  }
  __shared__ float red[4][2];
  const int wvv = tid >> 6;
  if ((tid & 63) == 0) { red[wvv][0] = S; red[wvv][1] = Q; }
  __syncthreads();
  const float St = red[0][0] + red[1][0] + red[2][0] + red[3][0];
  const float Qt = red[0][1] + red[1][1] + red[2][1] + red[3][1];
  const float cnt = (float)(16 << (2 * d_lw[lvl]));
  const float mean = St / cnt;
  const float var = Qt / cnt - mean * mean;
  const float rstd = rsqrtf(var + 1e-5f);

  const int pos = chunk * 256 + tid;
  if (pos >= 21824) return;            // only chunk 85 tail
  const int tower = ti >> 1;
  const float* gam = (tower ? g1 : g0) + plane * 8;
  const float* bet = (tower ? b1 : b0) + plane * 8;
  const size_t off = (size_t)ti * TIB + (size_t)plane * XP + (size_t)pos * 16;
  const uint4 d = *(const uint4*)((const char*)ybase + off);
  unsigned uu[4] = {d.x, d.y, d.z, d.w};
  unsigned ro[4];
#pragma unroll
  for (int k = 0; k < 4; k++) {
    const float f0 = __uint_as_float(uu[k] << 16);
    const float f1 = __uint_as_float(uu[k] & 0xFFFF0000u);
    const float o0 = fmaxf((f0 - mean) * rstd * gam[2 * k] + bet[2 * k], 0.f);
    const float o1 = fmaxf((f1 - mean) * rstd * gam[2 * k + 1] + bet[2 * k + 1], 0.f);
    ro[k] = (unsigned)f2bf(o0) | ((unsigned)f2bf(o1) << 16);
  }
  uint4 od = {ro[0], ro[1], ro[2], ro[3]};
  *(uint4*)((char*)xbase + off) = od;
}

// ---------------------------------------------------------------------------
extern "C" void kernel_launch(void* const* d_in, const int* in_sizes, int n_in,
                              void* d_out, int out_size, void* d_ws, size_t ws_size,
                              hipStream_t stream) {
  (void)in_sizes; (void)n_in; (void)out_size; (void)ws_size;
  char* ws = (char*)d_ws;
  unsigned short* zp = (unsigned short*)ws;                 // 1536 B zeros
  unsigned short* wblk = (unsigned short*)(ws + 2048);      // 8,257,536 B
  const size_t WSET_T = 1179648;                            // bytes per tower set
  const size_t WSET_O = 589824;                             // bytes per out set
  char* pXfeat = ws + 2048 + 6 * WSET_T + 2 * WSET_O;
  const size_t XSZ = (size_t)2 * 21824 * 256 * 2;           // 22,347,776 B
  char* pX = pXfeat + XSZ;                                  // 2 towers
  char* pY = pX + 2 * XSZ;                                  // 2 towers
  float* statsp = (float*)(pY + 2 * XSZ);                   // 163,840 float partials

  prep<<<dim3(2304, 10), 256, 0, stream>>>(
      (const float*)d_in[5], (const float*)d_in[9], (const float*)d_in[13],
      (const float*)d_in[17], (const float*)d_in[21], (const float*)d_in[25],
      (const float*)d_in[29], (const float*)d_in[31], (const float*)d_in[33],
      wblk, (float*)zp,
      (const float*)d_in[0], (const float*)d_in[1], (const float*)d_in[2],
      (const float*)d_in[3], (const float*)d_in[4], (unsigned short*)pXfeat);

  unsigned short* xc = (unsigned short*)pX;
  unsigned short* xr = (unsigned short*)(pX + XSZ);
  unsigned short* yc = (unsigned short*)pY;
  unsigned short* yr = (unsigned short*)(pY + XSZ);

  for (int s = 0; s < 3; s++) {
    const unsigned short* in0 = s ? xc : (unsigned short*)pXfeat;
    const unsigned short* in1 = s ? xr : (unsigned short*)pXfeat;
    const unsigned short* wc = wblk + (size_t)s * 589824;        // elem stride per set
    const unsigned short* wr = wblk + (size_t)(3 + s) * 589824;
    conv_mfma<<<1368, 256, 0, stream>>>(
        in0, in1, wc, wr, yc, yr,
        (const float*)d_in[6 + 4 * s], (const float*)d_in[18 + 4 * s],
        nullptr, nullptr, nullptr, nullptr, statsp, zp, 0);
    gn_apply<<<dim3(86, 32, 4), 256, 0, stream>>>(
        (const unsigned short*)pY, (unsigned short*)pX, statsp,
        (const float*)d_in[7 + 4 * s], (const float*)d_in[8 + 4 * s],
        (const float*)d_in[19 + 4 * s], (const float*)d_in[20 + 4 * s]);
  }
  const unsigned short* wo_c = wblk + (size_t)6 * 589824;
  const unsigned short* wo_r = wo_c + 294912;
  conv_mfma<<<684, 256, 0, stream>>>(
      xc, xr, wo_c, wo_r, nullptr, nullptr, nullptr, nullptr,
      (float*)d_out, (const float*)d_in[30], (const float*)d_in[32],
      (const float*)d_in[34], nullptr, zp, 1);
}